// Round 15
// baseline (60.210 us; speedup 1.0000x reference)
//
#include <hip/hip_runtime.h>
#include <hip/hip_bf16.h>
#include <math.h>

// Problem constants
#define BB 2
#define HH 64
#define WW 64
#define CC 128
#define NHD 4
#define HD 32
#define KS 7
#define KK 49
#define HID 512
#define NT (BB*HH*WW)   // 8192 tokens
#define WTS 196608      // elems per weight copy (qkv 49152 | proj 16384 | fc1 65536 | fc2 65536)

typedef __attribute__((ext_vector_type(8))) short bf16x8;
typedef __attribute__((ext_vector_type(4))) short bf16x4;
typedef __attribute__((ext_vector_type(4))) float f32x4;

__device__ __forceinline__ short f2bs(float v) {
    __hip_bfloat16 h = __float2bfloat16(v);
    return *reinterpret_cast<short*>(&h);
}

__device__ __forceinline__ f32x4 mfma16(bf16x4 a, bf16x4 b, f32x4 c) {
#if __has_builtin(__builtin_amdgcn_mfma_f32_16x16x16bf16_1k)
    return __builtin_amdgcn_mfma_f32_16x16x16bf16_1k(a, b, c, 0, 0, 0);
#else
    asm("v_mfma_f32_16x16x16_bf16 %0, %1, %2, %0" : "+v"(c) : "v"(a), "v"(b));
    return c;
#endif
}

// ---------------- prep: cast/transpose weights, 8 copies (one per XCD) ----------
__global__ void prep_cast(const float* __restrict__ qkv_w, const float* __restrict__ proj_w,
                          const float* __restrict__ fc1_w, const float* __restrict__ fc2_w,
                          __hip_bfloat16* __restrict__ wts) {
    int idx = blockIdx.x * 256 + threadIdx.x;
    const float* W; int K, N, off, base;
    if (idx < 49152)       { W = qkv_w;  K = 128; N = 384; off = idx;          base = 0; }
    else if (idx < 65536)  { W = proj_w; K = 128; N = 128; off = idx - 49152;  base = 49152; }
    else if (idx < 131072) { W = fc1_w;  K = 128; N = 512; off = idx - 65536;  base = 65536; }
    else                   { W = fc2_w;  K = 512; N = 128; off = idx - 131072; base = 131072; }
    int k = off / N, n = off - k * N;
    __hip_bfloat16 val = __float2bfloat16(W[(size_t)k * N + n]);
    int goff = base + n * K + k;
    #pragma unroll
    for (int c = 0; c < 8; ++c) wts[(size_t)c * WTS + goff] = val;
}

// ---------------- LN1 + QKV GEMM: 16 rows/block, 8 waves (48 cols each) ---------
// q,k: token-major [h][tok][32]; v: d-major vbT[h*32+d][tok].
__global__ void __launch_bounds__(512, 4)
qkv_ln_kernel(const float* __restrict__ x, const float* __restrict__ g,
              const float* __restrict__ bta, const __hip_bfloat16* __restrict__ wts,
              const float* __restrict__ qkv_b,
              __hip_bfloat16* __restrict__ qb, __hip_bfloat16* __restrict__ kb,
              __hip_bfloat16* __restrict__ vbT) {
    __shared__ ushort4 ys4[16 * 32];
    int tid = threadIdx.x;
    int R0 = blockIdx.x * 16;
    const __hip_bfloat16* qkv_wt = wts + (size_t)(blockIdx.x & 7) * WTS;

    { // LN1: 32 threads per row, 4 f32 each
        int row = tid >> 5, t32 = tid & 31;
        const float* xr = x + (size_t)(R0 + row) * CC + t32 * 4;
        float4 a0 = *(const float4*)xr;
        float s1 = a0.x + a0.y + a0.z + a0.w;
        float s2 = a0.x*a0.x + a0.y*a0.y + a0.z*a0.z + a0.w*a0.w;
        #pragma unroll
        for (int off = 1; off <= 16; off <<= 1) { s1 += __shfl_xor(s1, off); s2 += __shfl_xor(s2, off); }
        float mean = s1 * (1.0f / CC);
        float var  = s2 * (1.0f / CC) - mean * mean;
        float rstd = rsqrtf(var + 1e-5f);
        float4 g0 = *(const float4*)(g + t32 * 4);
        float4 b0 = *(const float4*)(bta + t32 * 4);
        ushort4 ch;
        ch.x = (unsigned short)f2bs((a0.x - mean) * rstd * g0.x + b0.x);
        ch.y = (unsigned short)f2bs((a0.y - mean) * rstd * g0.y + b0.y);
        ch.z = (unsigned short)f2bs((a0.z - mean) * rstd * g0.z + b0.z);
        ch.w = (unsigned short)f2bs((a0.w - mean) * rstd * g0.w + b0.w);
        int c = t32 >> 1;
        ys4[row * 32 + ((c ^ row) << 1) + (t32 & 1)] = ch;
    }
    __syncthreads();

    const bf16x8* ys8 = (const bf16x8*)ys4;
    int wid = tid >> 6, lane = tid & 63;
    int rowf = lane & 15, kg = lane >> 4;
    int n0 = wid * 48;

    bf16x8 a[4];
    #pragma unroll
    for (int t = 0; t < 4; ++t) a[t] = ys8[rowf * 16 + ((t * 4 + kg) ^ rowf)];

    f32x4 acc[3] = {};
    #pragma unroll
    for (int nf = 0; nf < 3; ++nf) {
        int col = n0 + nf * 16 + rowf;
        bf16x8 bfr[4];
        #pragma unroll
        for (int t = 0; t < 4; ++t)
            bfr[t] = *(const bf16x8*)(qkv_wt + (size_t)col * CC + t * 32 + kg * 8);
        #pragma unroll
        for (int t = 0; t < 4; ++t)
            acc[nf] = __builtin_amdgcn_mfma_f32_16x16x32_bf16(a[t], bfr[t], acc[nf], 0, 0, 0);
    }
    #pragma unroll
    for (int nf = 0; nf < 3; ++nf) {
        int col = n0 + nf * 16 + rowf;
        int which = col >> 7;           // 0=q,1=k,2=v (wave-uniform)
        int h = (col >> 5) & 3;
        int d = col & 31;
        float bv = qkv_b[col];
        if (which == 2) {
            ushort4 u;
            u.x = (unsigned short)f2bs(acc[nf][0] + bv);
            u.y = (unsigned short)f2bs(acc[nf][1] + bv);
            u.z = (unsigned short)f2bs(acc[nf][2] + bv);
            u.w = (unsigned short)f2bs(acc[nf][3] + bv);
            *(ushort4*)(vbT + ((size_t)(h * 32 + d) * NT + R0 + kg * 4)) = u;
        } else {
            __hip_bfloat16* dst = which == 0 ? qb : kb;
            #pragma unroll
            for (int r = 0; r < 4; ++r)
                dst[((size_t)h * NT + (R0 + kg * 4 + r)) * HD + d] = __float2bfloat16(acc[nf][r] + bv);
        }
    }
}

// ---------------- MEGA TAIL: 16 tokens/block, 8 waves, grid 512 ------------------
#define X1P 132          // x1s row stride (f32)
#define H1P 520          // h1s row stride (bf16)
__global__ void __launch_bounds__(512, 4)
mega_tail(const __hip_bfloat16* __restrict__ qb, const __hip_bfloat16* __restrict__ kb,
          const __hip_bfloat16* __restrict__ vbT, const float* __restrict__ rpb,
          const float* __restrict__ x, const __hip_bfloat16* __restrict__ wts,
          const float* __restrict__ proj_b,
          const float* __restrict__ n2g, const float* __restrict__ n2b,
          const float* __restrict__ fc1_b, const float* __restrict__ fc2_b,
          float* __restrict__ out) {
    __shared__ float rpbs[720];         // 16-pad + 4*169; pre-scaled by log2e
    __shared__ ushort4 ysA4[16 * 32];   // attn out, reused for LN2 out
    __shared__ float x1s[16 * X1P];
    __shared__ short h1s[16 * H1P];
    __shared__ float mlbuf[4][2][16];   // [h][{m,l}][q] from p=1 waves
    __shared__ float obuf[4][32][17];   // [h][d][q] padded, from p=1 waves
    int tid = threadIdx.x;
    int R0 = blockIdx.x * 16;
    int wid = tid >> 6, lane = tid & 63;
    int rowf = lane & 15, kg = lane >> 4;
    const __hip_bfloat16* wbase = wts + (size_t)(blockIdx.x & 7) * WTS;
    const __hip_bfloat16* proj_wt = wbase + 49152;
    const __hip_bfloat16* fc1_wt  = wbase + 65536;
    const __hip_bfloat16* fc2_wt  = wbase + 131072;

    for (int idx = tid; idx < NHD * 169; idx += 512)
        rpbs[16 + idx] = rpb[idx] * 1.4426950408889634f;
    __syncthreads();

    // ---- Phase A: MFMA attention; wave = (head h, tile-half p) -----------------
    {
        const int h = wid & 3;
        const int p = wid >> 2;
        const int q = rowf;
        int j0 = R0 & 63;
        int i  = (R0 >> 6) & 63;
        int b  = R0 >> 12;
        int si = i - 3; si = si < 0 ? 0 : (si > 57 ? 57 : si);
        int sjm = j0 - 3; sjm = sjm < 0 ? 0 : (sjm > 57 ? 57 : sjm);
        sjm &= ~1;                      // even for 8B-aligned vbT loads
        int oi = si - i + 6;
        int jq = j0 + q;
        int sjq = jq - 3; sjq = sjq < 0 ? 0 : (sjq > 57 ? 57 : sjq);
        int lo = sjq - sjm;
        int ojq = sjm - jq + 6;
        int rb0 = (b * 64 + si) * 64;

        bf16x8 qf = *(const bf16x8*)(qb + ((size_t)h * NT + R0 + q) * HD + kg * 8);
        const __hip_bfloat16* kb_h = kb + (size_t)h * NT * HD;

        // S^T = K·Q^T : this wave's 7 of 14 tiles (kt = p*7 + u)
        f32x4 s[7];
        #pragma unroll
        for (int u = 0; u < 7; ++u) {
            int kt = p * 7 + u;
            int a = kt >> 1;
            int cb = (kt & 1) * 16;
            int col = q + cb + sjm; col = col > 63 ? 63 : col;
            int tok = rb0 + a * 64 + col;
            bf16x8 kf = *(const bf16x8*)(kb_h + (size_t)tok * HD + kg * 8);
            f32x4 z = {0.f, 0.f, 0.f, 0.f};
            s[u] = __builtin_amdgcn_mfma_f32_16x16x32_bf16(kf, qf, z, 0, 0, 0);
        }
        // mask + bias (log2-domain) + local max
        const float* rb_h = rpbs + 16 + h * 169 + oi * 13;
        float m = -1e30f;
        #pragma unroll
        for (int u = 0; u < 7; ++u) {
            int kt = p * 7 + u;
            int a = kt >> 1;
            int cb = (kt & 1) * 16;
            const float* bp = rb_h + a * 13 + (ojq + cb + kg * 4);
            #pragma unroll
            for (int r = 0; r < 4; ++r) {
                int c = cb + kg * 4 + r;
                bool valid = (unsigned)(c - lo) < 7u;
                float z = s[u][r] * 0.25506948f + bp[r];   // (1/sqrt32)*log2e
                s[u][r] = valid ? z : -1e30f;
                m = fmaxf(m, s[u][r]);
            }
        }
        m = fmaxf(m, __shfl_xor(m, 16));
        m = fmaxf(m, __shfl_xor(m, 32));

        // local P = exp2(S-m); partial O^T = V^T·P^T (zero-shuffle)
        float l = 0.0f;
        f32x4 o0 = {0.f,0.f,0.f,0.f}, o1 = {0.f,0.f,0.f,0.f};
        const __hip_bfloat16* vt_l = vbT + ((size_t)(h * 32) + q) * NT;
        #pragma unroll
        for (int u = 0; u < 7; ++u) {
            int kt = p * 7 + u;
            int a = kt >> 1;
            int cb = (kt & 1) * 16;
            bf16x4 pb;
            #pragma unroll
            for (int r = 0; r < 4; ++r) {
                float pv = exp2f(s[u][r] - m);
                l += pv;
                pb[r] = f2bs(pv);
            }
            int colb = cb + kg * 4 + sjm; colb = colb > 60 ? 60 : colb;
            int tokb = rb0 + a * 64 + colb;
            bf16x4 v0 = *(const bf16x4*)(vt_l + tokb);
            bf16x4 v1 = *(const bf16x4*)(vt_l + (size_t)16 * NT + tokb);
            o0 = mfma16(v0, pb, o0);
            o1 = mfma16(v1, pb, o1);
        }
        l += __shfl_xor(l, 16);
        l += __shfl_xor(l, 32);

        if (p == 1) {
            if (kg == 0) { mlbuf[h][0][q] = m; mlbuf[h][1][q] = l; }
            #pragma unroll
            for (int r = 0; r < 4; ++r) {
                obuf[h][kg * 4 + r][q]      = o0[r];
                obuf[h][16 + kg * 4 + r][q] = o1[r];
            }
        }
        __syncthreads();
        if (p == 0) {
            float m1 = mlbuf[h][0][q];
            float l1 = mlbuf[h][1][q];
            float M  = fmaxf(m, m1);
            float e0 = exp2f(m - M);
            float e1 = exp2f(m1 - M);
            float inv = 1.0f / (l * e0 + l1 * e1);
            #pragma unroll
            for (int mt = 0; mt < 2; ++mt) {
                f32x4 ov = mt ? o1 : o0;
                ushort4 u4;
                float v0 = (ov[0] * e0 + obuf[h][mt * 16 + kg * 4 + 0][q] * e1) * inv;
                float v1 = (ov[1] * e0 + obuf[h][mt * 16 + kg * 4 + 1][q] * e1) * inv;
                float v2 = (ov[2] * e0 + obuf[h][mt * 16 + kg * 4 + 2][q] * e1) * inv;
                float v3 = (ov[3] * e0 + obuf[h][mt * 16 + kg * 4 + 3][q] * e1) * inv;
                u4.x = (unsigned short)f2bs(v0);
                u4.y = (unsigned short)f2bs(v1);
                u4.z = (unsigned short)f2bs(v2);
                u4.w = (unsigned short)f2bs(v3);
                int cch = h * 4 + mt * 2 + (kg >> 1);
                ysA4[q * 32 + ((cch ^ q) << 1) + (kg & 1)] = u4;
            }
        }
    }
    __syncthreads();

    // ---- Phase B: proj (wave w covers 16 cols), K=128 from LDS attn tile -------
    {
        const bf16x8* ysA8 = (const bf16x8*)ysA4;
        bf16x8 a[4];
        #pragma unroll
        for (int t = 0; t < 4; ++t)
            a[t] = ysA8[rowf * 16 + ((t * 4 + kg) ^ rowf)];
        int col = wid * 16 + rowf;
        bf16x8 bfr[4];
        #pragma unroll
        for (int t = 0; t < 4; ++t)
            bfr[t] = *(const bf16x8*)(proj_wt + (size_t)col * CC + t * 32 + kg * 8);
        f32x4 acc = {};
        #pragma unroll
        for (int t = 0; t < 4; ++t)
            acc = __builtin_amdgcn_mfma_f32_16x16x32_bf16(a[t], bfr[t], acc, 0, 0, 0);
        float bv = proj_b[col];
        #pragma unroll
        for (int r = 0; r < 4; ++r) {
            int row = kg * 4 + r;
            x1s[row * X1P + col] = acc[r] + bv + x[(size_t)(R0 + row) * CC + col];
        }
    }
    __syncthreads();

    // ---- Phase C: LN2 (32 threads/row) -> ysA4 (reused) ------------------------
    {
        int row = tid >> 5, t32 = tid & 31;
        float4 a0 = *(const float4*)&x1s[row * X1P + t32 * 4];
        float s1 = a0.x + a0.y + a0.z + a0.w;
        float s2 = a0.x*a0.x + a0.y*a0.y + a0.z*a0.z + a0.w*a0.w;
        #pragma unroll
        for (int off = 1; off <= 16; off <<= 1) { s1 += __shfl_xor(s1, off); s2 += __shfl_xor(s2, off); }
        float mean = s1 * (1.0f / CC);
        float var  = s2 * (1.0f / CC) - mean * mean;
        float rstd = rsqrtf(var + 1e-5f);
        float4 g0 = *(const float4*)(n2g + t32 * 4);
        float4 b0 = *(const float4*)(n2b + t32 * 4);
        ushort4 ch;
        ch.x = (unsigned short)f2bs((a0.x - mean) * rstd * g0.x + b0.x);
        ch.y = (unsigned short)f2bs((a0.y - mean) * rstd * g0.y + b0.y);
        ch.z = (unsigned short)f2bs((a0.z - mean) * rstd * g0.z + b0.z);
        ch.w = (unsigned short)f2bs((a0.w - mean) * rstd * g0.w + b0.w);
        int c = t32 >> 1;
        ysA4[row * 32 + ((c ^ row) << 1) + (t32 & 1)] = ch;
    }
    __syncthreads();

    // ---- Phase D: FC1 + gelu (wave w covers 64 cols) ---------------------------
    {
        const bf16x8* ys8 = (const bf16x8*)ysA4;
        bf16x8 a[4];
        #pragma unroll
        for (int t = 0; t < 4; ++t) a[t] = ys8[rowf * 16 + ((t * 4 + kg) ^ rowf)];
        int n0 = wid * 64;
        f32x4 acc4[4] = {};
        #pragma unroll
        for (int nf = 0; nf < 4; ++nf) {
            int col = n0 + nf * 16 + rowf;
            bf16x8 bfr[4];
            #pragma unroll
            for (int t = 0; t < 4; ++t)
                bfr[t] = *(const bf16x8*)(fc1_wt + (size_t)col * CC + t * 32 + kg * 8);
            #pragma unroll
            for (int t = 0; t < 4; ++t)
                acc4[nf] = __builtin_amdgcn_mfma_f32_16x16x32_bf16(a[t], bfr[t], acc4[nf], 0, 0, 0);
        }
        #pragma unroll
        for (int nf = 0; nf < 4; ++nf) {
            int col = n0 + nf * 16 + rowf;
            float bv = fc1_b[col];
            #pragma unroll
            for (int r = 0; r < 4; ++r) {
                int row = kg * 4 + r;
                float v = acc4[nf][r] + bv;
                v = 0.5f * v * (1.0f + erff(v * 0.70710678118654752f));
                h1s[row * H1P + col] = f2bs(v);
            }
        }
    }
    __syncthreads();

    // ---- Phase E: FC2 + resid (wave w covers 16 cols), K=512 from LDS ----------
    {
        int col = wid * 16 + rowf;
        f32x4 acc = {};
        #pragma unroll
        for (int kc = 0; kc < 512; kc += 128) {
            bf16x8 a[4], bfr[4];
            #pragma unroll
            for (int t = 0; t < 4; ++t)
                a[t] = *(const bf16x8*)&h1s[rowf * H1P + kc + t * 32 + kg * 8];
            #pragma unroll
            for (int t = 0; t < 4; ++t)
                bfr[t] = *(const bf16x8*)(fc2_wt + (size_t)col * HID + kc + t * 32 + kg * 8);
            #pragma unroll
            for (int t = 0; t < 4; ++t)
                acc = __builtin_amdgcn_mfma_f32_16x16x32_bf16(a[t], bfr[t], acc, 0, 0, 0);
        }
        float bv = fc2_b[col];
        #pragma unroll
        for (int r = 0; r < 4; ++r) {
            int row = kg * 4 + r;
            out[(size_t)(R0 + row) * CC + col] = acc[r] + bv + x1s[row * X1P + col];
        }
    }
}

extern "C" void kernel_launch(void* const* d_in, const int* in_sizes, int n_in,
                              void* d_out, int out_size, void* d_ws, size_t ws_size,
                              hipStream_t stream) {
    const float* x       = (const float*)d_in[0];
    const float* norm1_g = (const float*)d_in[1];
    const float* norm1_b = (const float*)d_in[2];
    const float* qkv_w   = (const float*)d_in[3];
    const float* qkv_b   = (const float*)d_in[4];
    const float* rpb     = (const float*)d_in[5];
    const float* proj_w  = (const float*)d_in[6];
    const float* proj_b  = (const float*)d_in[7];
    const float* norm2_g = (const float*)d_in[8];
    const float* norm2_b = (const float*)d_in[9];
    const float* fc1_w   = (const float*)d_in[10];
    const float* fc1_b   = (const float*)d_in[11];
    const float* fc2_w   = (const float*)d_in[12];
    const float* fc2_b   = (const float*)d_in[13];
    float* out = (float*)d_out;
    char* ws = (char*)d_ws;

    // workspace: qb [4][8192][32], kb, vbT [128][8192] (2MB each); wts 8 copies
    __hip_bfloat16* qb  = (__hip_bfloat16*)(ws);
    __hip_bfloat16* kb  = (__hip_bfloat16*)(ws + 2097152);
    __hip_bfloat16* vbT = (__hip_bfloat16*)(ws + 4194304);
    __hip_bfloat16* wts = (__hip_bfloat16*)(ws + 6291456);  // 8 x 196608 bf16 = 3 MB

    prep_cast<<<768, 256, 0, stream>>>(qkv_w, proj_w, fc1_w, fc2_w, wts);
    qkv_ln_kernel<<<NT / 16, 512, 0, stream>>>(x, norm1_g, norm1_b, wts, qkv_b,
                                               qb, kb, vbT);
    mega_tail<<<NT / 16, 512, 0, stream>>>(qb, kb, vbT, rpb, x, wts, proj_b,
                                           norm2_g, norm2_b, fc1_b, fc2_b, out);
}

// Round 16
// 43.650 us; speedup vs baseline: 1.3794x; 1.3794x over previous
//
#include <hip/hip_runtime.h>
#include <hip/hip_bf16.h>
#include <math.h>

// Problem constants
#define BB 2
#define HH 64
#define WW 64
#define CC 128
#define NHD 4
#define HD 32
#define KS 7
#define KK 49
#define HID 512
#define NT (BB*HH*WW)   // 8192 tokens
#define WTS 196608      // elems (qkv 49152 | proj 16384 | fc1 65536 | fc2 65536)

typedef __attribute__((ext_vector_type(8))) short bf16x8;
typedef __attribute__((ext_vector_type(4))) short bf16x4;
typedef __attribute__((ext_vector_type(4))) float f32x4;

__device__ __forceinline__ short f2bs(float v) {
    __hip_bfloat16 h = __float2bfloat16(v);
    return *reinterpret_cast<short*>(&h);
}

__device__ __forceinline__ f32x4 mfma16(bf16x4 a, bf16x4 b, f32x4 c) {
#if __has_builtin(__builtin_amdgcn_mfma_f32_16x16x16bf16_1k)
    return __builtin_amdgcn_mfma_f32_16x16x16bf16_1k(a, b, c, 0, 0, 0);
#else
    asm("v_mfma_f32_16x16x16_bf16 %0, %1, %2, %0" : "+v"(c) : "v"(a), "v"(b));
    return c;
#endif
}

// ---------------- prep: cast/transpose weights, single copy ---------------------
__global__ void prep_cast(const float* __restrict__ qkv_w, const float* __restrict__ proj_w,
                          const float* __restrict__ fc1_w, const float* __restrict__ fc2_w,
                          __hip_bfloat16* __restrict__ wts) {
    int idx = blockIdx.x * 256 + threadIdx.x;
    const float* W; int K, N, off, base;
    if (idx < 49152)       { W = qkv_w;  K = 128; N = 384; off = idx;          base = 0; }
    else if (idx < 65536)  { W = proj_w; K = 128; N = 128; off = idx - 49152;  base = 49152; }
    else if (idx < 131072) { W = fc1_w;  K = 128; N = 512; off = idx - 65536;  base = 65536; }
    else                   { W = fc2_w;  K = 512; N = 128; off = idx - 131072; base = 131072; }
    int k = off / N, n = off - k * N;
    wts[base + n * K + k] = __float2bfloat16(W[(size_t)k * N + n]);
}

// ---------------- LN1 + QKV GEMM: 32 rows/block, 8 waves (48 cols x M=32) -------
// q,k: token-major [h][tok][32]; v: d-major vbT[h*32+d][tok].
__global__ void __launch_bounds__(512, 2)
qkv_ln_kernel(const float* __restrict__ x, const float* __restrict__ g,
              const float* __restrict__ bta, const __hip_bfloat16* __restrict__ wts,
              const float* __restrict__ qkv_b,
              __hip_bfloat16* __restrict__ qb, __hip_bfloat16* __restrict__ kb,
              __hip_bfloat16* __restrict__ vbT) {
    __shared__ ushort4 ys4[32 * 32];    // 8 KB
    int tid = threadIdx.x;
    int R0 = blockIdx.x * 32;
    const __hip_bfloat16* qkv_wt = wts;

    #pragma unroll
    for (int gg = 0; gg < 2; ++gg) {    // LN1: 32 rows, 32 threads/row
        int row = gg * 16 + (tid >> 5), t32 = tid & 31;
        const float* xr = x + (size_t)(R0 + row) * CC + t32 * 4;
        float4 a0 = *(const float4*)xr;
        float s1 = a0.x + a0.y + a0.z + a0.w;
        float s2 = a0.x*a0.x + a0.y*a0.y + a0.z*a0.z + a0.w*a0.w;
        #pragma unroll
        for (int off = 1; off <= 16; off <<= 1) { s1 += __shfl_xor(s1, off); s2 += __shfl_xor(s2, off); }
        float mean = s1 * (1.0f / CC);
        float var  = s2 * (1.0f / CC) - mean * mean;
        float rstd = rsqrtf(var + 1e-5f);
        float4 g0 = *(const float4*)(g + t32 * 4);
        float4 b0 = *(const float4*)(bta + t32 * 4);
        ushort4 ch;
        ch.x = (unsigned short)f2bs((a0.x - mean) * rstd * g0.x + b0.x);
        ch.y = (unsigned short)f2bs((a0.y - mean) * rstd * g0.y + b0.y);
        ch.z = (unsigned short)f2bs((a0.z - mean) * rstd * g0.z + b0.z);
        ch.w = (unsigned short)f2bs((a0.w - mean) * rstd * g0.w + b0.w);
        int c = t32 >> 1;
        ys4[row * 32 + ((c ^ (row & 15)) << 1) + (t32 & 1)] = ch;
    }
    __syncthreads();

    const bf16x8* ys8 = (const bf16x8*)ys4;
    int wid = tid >> 6, lane = tid & 63;
    int rowf = lane & 15, kg = lane >> 4;
    int n0 = wid * 48;

    bf16x8 a2[2][4];
    #pragma unroll
    for (int mt = 0; mt < 2; ++mt) {
        int rr = mt * 16 + rowf;
        #pragma unroll
        for (int t = 0; t < 4; ++t)
            a2[mt][t] = ys8[rr * 16 + ((t * 4 + kg) ^ (rr & 15))];
    }

    f32x4 acc[3][2] = {};
    #pragma unroll
    for (int nf = 0; nf < 3; ++nf) {
        int col = n0 + nf * 16 + rowf;
        bf16x8 bfr[4];
        #pragma unroll
        for (int t = 0; t < 4; ++t)
            bfr[t] = *(const bf16x8*)(qkv_wt + (size_t)col * CC + t * 32 + kg * 8);
        #pragma unroll
        for (int t = 0; t < 4; ++t)
            #pragma unroll
            for (int mt = 0; mt < 2; ++mt)
                acc[nf][mt] = __builtin_amdgcn_mfma_f32_16x16x32_bf16(a2[mt][t], bfr[t], acc[nf][mt], 0, 0, 0);
    }
    #pragma unroll
    for (int nf = 0; nf < 3; ++nf) {
        int col = n0 + nf * 16 + rowf;
        int which = col >> 7;           // 0=q,1=k,2=v (wave-uniform)
        int h = (col >> 5) & 3;
        int d = col & 31;
        float bv = qkv_b[col];
        #pragma unroll
        for (int mt = 0; mt < 2; ++mt) {
            if (which == 2) {
                ushort4 u;
                u.x = (unsigned short)f2bs(acc[nf][mt][0] + bv);
                u.y = (unsigned short)f2bs(acc[nf][mt][1] + bv);
                u.z = (unsigned short)f2bs(acc[nf][mt][2] + bv);
                u.w = (unsigned short)f2bs(acc[nf][mt][3] + bv);
                *(ushort4*)(vbT + ((size_t)(h * 32 + d) * NT + R0 + mt * 16 + kg * 4)) = u;
            } else {
                __hip_bfloat16* dst = which == 0 ? qb : kb;
                #pragma unroll
                for (int r = 0; r < 4; ++r)
                    dst[((size_t)h * NT + (R0 + mt * 16 + kg * 4 + r)) * HD + d] = __float2bfloat16(acc[nf][mt][r] + bv);
            }
        }
    }
}

// ---------------- MEGA TAIL: 32 tokens/block, 8 waves, grid 256 ------------------
#define X1P 132          // x1s row stride (f32)
#define H1P 520          // h1s row stride (bf16)
__global__ void __launch_bounds__(512, 2)
mega_tail(const __hip_bfloat16* __restrict__ qb, const __hip_bfloat16* __restrict__ kb,
          const __hip_bfloat16* __restrict__ vbT, const float* __restrict__ rpb,
          const float* __restrict__ x, const __hip_bfloat16* __restrict__ wts,
          const float* __restrict__ proj_b,
          const float* __restrict__ n2g, const float* __restrict__ n2b,
          const float* __restrict__ fc1_b, const float* __restrict__ fc2_b,
          float* __restrict__ out) {
    __shared__ float rpbs[720];         // 16-pad + 4*169; pre-scaled by log2e
    __shared__ ushort4 ysA4[32 * 32];   // 8 KB: attn out, reused for LN2 out
    __shared__ float x1s[32 * X1P];     // 16.9 KB
    __shared__ short h1s[32 * H1P];     // 33.3 KB
    int tid = threadIdx.x;
    int R0 = blockIdx.x * 32;
    int wid = tid >> 6, lane = tid & 63;
    int rowf = lane & 15, kg = lane >> 4;
    const __hip_bfloat16* proj_wt = wts + 49152;
    const __hip_bfloat16* fc1_wt  = wts + 65536;
    const __hip_bfloat16* fc2_wt  = wts + 131072;

    for (int idx = tid; idx < NHD * 169; idx += 512)
        rpbs[16 + idx] = rpb[idx] * 1.4426950408889634f;
    __syncthreads();

    // ---- Phase A: MFMA attention; wave = (head h, q-group qg) ------------------
    {
        const int h  = wid & 3;
        const int qg = wid >> 2;
        const int R0g = R0 + qg * 16;
        const int q = rowf;
        int j0 = R0g & 63;
        int i  = (R0g >> 6) & 63;
        int b  = R0g >> 12;
        int si = i - 3; si = si < 0 ? 0 : (si > 57 ? 57 : si);
        int sjm = j0 - 3; sjm = sjm < 0 ? 0 : (sjm > 57 ? 57 : sjm);
        sjm &= ~1;                      // even for 8B-aligned vbT loads
        int oi = si - i + 6;
        int jq = j0 + q;
        int sjq = jq - 3; sjq = sjq < 0 ? 0 : (sjq > 57 ? 57 : sjq);
        int lo = sjq - sjm;
        int ojq = sjm - jq + 6;
        int rb0 = (b * 64 + si) * 64;

        bf16x8 qf = *(const bf16x8*)(qb + ((size_t)h * NT + R0g + q) * HD + kg * 8);
        const __hip_bfloat16* kb_h = kb + (size_t)h * NT * HD;

        // S^T = K·Q^T : 14 tiles (7 window rows x 2 col-tiles)
        f32x4 s[14];
        #pragma unroll
        for (int kt = 0; kt < 14; ++kt) {
            const int a = kt >> 1;
            const int cb = (kt & 1) * 16;
            int col = q + cb + sjm; col = col > 63 ? 63 : col;
            int tok = rb0 + a * 64 + col;
            bf16x8 kf = *(const bf16x8*)(kb_h + (size_t)tok * HD + kg * 8);
            f32x4 z = {0.f, 0.f, 0.f, 0.f};
            s[kt] = __builtin_amdgcn_mfma_f32_16x16x32_bf16(kf, qf, z, 0, 0, 0);
        }
        // mask + bias (log2-domain) + row max
        const float* rb_h = rpbs + 16 + h * 169 + oi * 13;
        float m = -1e30f;
        #pragma unroll
        for (int kt = 0; kt < 14; ++kt) {
            const int a = kt >> 1;
            const int cb = (kt & 1) * 16;
            const float* bp = rb_h + a * 13 + (ojq + cb + kg * 4);
            #pragma unroll
            for (int r = 0; r < 4; ++r) {
                int c = cb + kg * 4 + r;
                bool valid = (unsigned)(c - lo) < 7u;
                float z = s[kt][r] * 0.25506948f + bp[r];   // (1/sqrt32)*log2e
                s[kt][r] = valid ? z : -1e30f;
                m = fmaxf(m, s[kt][r]);
            }
        }
        m = fmaxf(m, __shfl_xor(m, 16));
        m = fmaxf(m, __shfl_xor(m, 32));

        // P = exp2(S-m); O^T = V^T·P^T (zero-shuffle, P lane-local)
        float l = 0.0f;
        f32x4 o0 = {0.f,0.f,0.f,0.f}, o1 = {0.f,0.f,0.f,0.f};
        const __hip_bfloat16* vt_l = vbT + ((size_t)(h * 32) + q) * NT;
        #pragma unroll
        for (int kt = 0; kt < 14; ++kt) {
            const int a = kt >> 1;
            const int cb = (kt & 1) * 16;
            bf16x4 pb;
            #pragma unroll
            for (int r = 0; r < 4; ++r) {
                float pv = exp2f(s[kt][r] - m);
                l += pv;
                pb[r] = f2bs(pv);
            }
            int colb = cb + kg * 4 + sjm; colb = colb > 60 ? 60 : colb;
            int tokb = rb0 + a * 64 + colb;
            bf16x4 v0 = *(const bf16x4*)(vt_l + tokb);
            bf16x4 v1 = *(const bf16x4*)(vt_l + (size_t)16 * NT + tokb);
            o0 = mfma16(v0, pb, o0);
            o1 = mfma16(v1, pb, o1);
        }
        l += __shfl_xor(l, 16);
        l += __shfl_xor(l, 32);
        float inv = 1.0f / l;

        int lt = qg * 16 + q;
        #pragma unroll
        for (int mt = 0; mt < 2; ++mt) {
            f32x4 ov = mt ? o1 : o0;
            ushort4 u4;
            u4.x = (unsigned short)f2bs(ov[0] * inv);
            u4.y = (unsigned short)f2bs(ov[1] * inv);
            u4.z = (unsigned short)f2bs(ov[2] * inv);
            u4.w = (unsigned short)f2bs(ov[3] * inv);
            int cch = h * 4 + mt * 2 + (kg >> 1);
            ysA4[lt * 32 + ((cch ^ q) << 1) + (kg & 1)] = u4;
        }
    }
    __syncthreads();

    // ---- Phase B: proj (wave w covers 16 cols, M=32) ---------------------------
    {
        const bf16x8* ysA8 = (const bf16x8*)ysA4;
        bf16x8 a2[2][4];
        #pragma unroll
        for (int mt = 0; mt < 2; ++mt) {
            int rr = mt * 16 + rowf;
            #pragma unroll
            for (int t = 0; t < 4; ++t)
                a2[mt][t] = ysA8[rr * 16 + ((t * 4 + kg) ^ (rr & 15))];
        }
        int col = wid * 16 + rowf;
        bf16x8 bfr[4];
        #pragma unroll
        for (int t = 0; t < 4; ++t)
            bfr[t] = *(const bf16x8*)(proj_wt + (size_t)col * CC + t * 32 + kg * 8);
        f32x4 acc[2] = {};
        #pragma unroll
        for (int t = 0; t < 4; ++t)
            #pragma unroll
            for (int mt = 0; mt < 2; ++mt)
                acc[mt] = __builtin_amdgcn_mfma_f32_16x16x32_bf16(a2[mt][t], bfr[t], acc[mt], 0, 0, 0);
        float bv = proj_b[col];
        #pragma unroll
        for (int mt = 0; mt < 2; ++mt)
            #pragma unroll
            for (int r = 0; r < 4; ++r) {
                int row = mt * 16 + kg * 4 + r;
                x1s[row * X1P + col] = acc[mt][r] + bv + x[(size_t)(R0 + row) * CC + col];
            }
    }
    __syncthreads();

    // ---- Phase C: LN2 (32 rows, 2 iterations) -> ysA4 (reused) -----------------
    #pragma unroll
    for (int gg = 0; gg < 2; ++gg) {
        int row = gg * 16 + (tid >> 5), t32 = tid & 31;
        float4 a0 = *(const float4*)&x1s[row * X1P + t32 * 4];
        float s1 = a0.x + a0.y + a0.z + a0.w;
        float s2 = a0.x*a0.x + a0.y*a0.y + a0.z*a0.z + a0.w*a0.w;
        #pragma unroll
        for (int off = 1; off <= 16; off <<= 1) { s1 += __shfl_xor(s1, off); s2 += __shfl_xor(s2, off); }
        float mean = s1 * (1.0f / CC);
        float var  = s2 * (1.0f / CC) - mean * mean;
        float rstd = rsqrtf(var + 1e-5f);
        float4 g0 = *(const float4*)(n2g + t32 * 4);
        float4 b0 = *(const float4*)(n2b + t32 * 4);
        ushort4 ch;
        ch.x = (unsigned short)f2bs((a0.x - mean) * rstd * g0.x + b0.x);
        ch.y = (unsigned short)f2bs((a0.y - mean) * rstd * g0.y + b0.y);
        ch.z = (unsigned short)f2bs((a0.z - mean) * rstd * g0.z + b0.z);
        ch.w = (unsigned short)f2bs((a0.w - mean) * rstd * g0.w + b0.w);
        int c = t32 >> 1;
        ysA4[row * 32 + ((c ^ (row & 15)) << 1) + (t32 & 1)] = ch;
    }
    __syncthreads();

    // ---- Phase D: FC1 + gelu (wave w covers 64 cols, M=32) ---------------------
    {
        const bf16x8* ys8 = (const bf16x8*)ysA4;
        bf16x8 a2[2][4];
        #pragma unroll
        for (int mt = 0; mt < 2; ++mt) {
            int rr = mt * 16 + rowf;
            #pragma unroll
            for (int t = 0; t < 4; ++t)
                a2[mt][t] = ys8[rr * 16 + ((t * 4 + kg) ^ (rr & 15))];
        }
        int n0 = wid * 64;
        f32x4 acc[4][2] = {};
        #pragma unroll
        for (int nf = 0; nf < 4; ++nf) {
            int col = n0 + nf * 16 + rowf;
            bf16x8 bfr[4];
            #pragma unroll
            for (int t = 0; t < 4; ++t)
                bfr[t] = *(const bf16x8*)(fc1_wt + (size_t)col * CC + t * 32 + kg * 8);
            #pragma unroll
            for (int t = 0; t < 4; ++t)
                #pragma unroll
                for (int mt = 0; mt < 2; ++mt)
                    acc[nf][mt] = __builtin_amdgcn_mfma_f32_16x16x32_bf16(a2[mt][t], bfr[t], acc[nf][mt], 0, 0, 0);
        }
        #pragma unroll
        for (int nf = 0; nf < 4; ++nf) {
            int col = n0 + nf * 16 + rowf;
            float bv = fc1_b[col];
            #pragma unroll
            for (int mt = 0; mt < 2; ++mt)
                #pragma unroll
                for (int r = 0; r < 4; ++r) {
                    int row = mt * 16 + kg * 4 + r;
                    float v = acc[nf][mt][r] + bv;
                    v = 0.5f * v * (1.0f + erff(v * 0.70710678118654752f));
                    h1s[row * H1P + col] = f2bs(v);
                }
        }
    }
    __syncthreads();

    // ---- Phase E: FC2 + resid (wave w covers 16 cols, M=32), K=512 from LDS ----
    {
        int col = wid * 16 + rowf;
        f32x4 acc[2] = {};
        #pragma unroll
        for (int kc = 0; kc < 512; kc += 128) {
            bf16x8 a2e[2][4], bfr[4];
            #pragma unroll
            for (int mt = 0; mt < 2; ++mt) {
                int rr = mt * 16 + rowf;
                #pragma unroll
                for (int t = 0; t < 4; ++t)
                    a2e[mt][t] = *(const bf16x8*)&h1s[rr * H1P + kc + t * 32 + kg * 8];
            }
            #pragma unroll
            for (int t = 0; t < 4; ++t)
                bfr[t] = *(const bf16x8*)(fc2_wt + (size_t)col * HID + kc + t * 32 + kg * 8);
            #pragma unroll
            for (int t = 0; t < 4; ++t)
                #pragma unroll
                for (int mt = 0; mt < 2; ++mt)
                    acc[mt] = __builtin_amdgcn_mfma_f32_16x16x32_bf16(a2e[mt][t], bfr[t], acc[mt], 0, 0, 0);
        }
        float bv = fc2_b[col];
        #pragma unroll
        for (int mt = 0; mt < 2; ++mt)
            #pragma unroll
            for (int r = 0; r < 4; ++r) {
                int row = mt * 16 + kg * 4 + r;
                out[(size_t)(R0 + row) * CC + col] = acc[mt][r] + bv + x1s[row * X1P + col];
            }
    }
}

extern "C" void kernel_launch(void* const* d_in, const int* in_sizes, int n_in,
                              void* d_out, int out_size, void* d_ws, size_t ws_size,
                              hipStream_t stream) {
    const float* x       = (const float*)d_in[0];
    const float* norm1_g = (const float*)d_in[1];
    const float* norm1_b = (const float*)d_in[2];
    const float* qkv_w   = (const float*)d_in[3];
    const float* qkv_b   = (const float*)d_in[4];
    const float* rpb     = (const float*)d_in[5];
    const float* proj_w  = (const float*)d_in[6];
    const float* proj_b  = (const float*)d_in[7];
    const float* norm2_g = (const float*)d_in[8];
    const float* norm2_b = (const float*)d_in[9];
    const float* fc1_w   = (const float*)d_in[10];
    const float* fc1_b   = (const float*)d_in[11];
    const float* fc2_w   = (const float*)d_in[12];
    const float* fc2_b   = (const float*)d_in[13];
    float* out = (float*)d_out;
    char* ws = (char*)d_ws;

    // workspace: qb [4][8192][32], kb, vbT [128][8192] (2MB each); wts single copy
    __hip_bfloat16* qb  = (__hip_bfloat16*)(ws);
    __hip_bfloat16* kb  = (__hip_bfloat16*)(ws + 2097152);
    __hip_bfloat16* vbT = (__hip_bfloat16*)(ws + 4194304);
    __hip_bfloat16* wts = (__hip_bfloat16*)(ws + 6291456);  // 196608 bf16 = 384 KB

    prep_cast<<<768, 256, 0, stream>>>(qkv_w, proj_w, fc1_w, fc2_w, wts);
    qkv_ln_kernel<<<NT / 32, 512, 0, stream>>>(x, norm1_g, norm1_b, wts, qkv_b,
                                               qb, kb, vbT);
    mega_tail<<<NT / 32, 512, 0, stream>>>(qb, kb, vbT, rpb, x, wts, proj_b,
                                           norm2_g, norm2_b, fc1_b, fc2_b, out);
}

// Round 17
// 43.256 us; speedup vs baseline: 1.3919x; 1.0091x over previous
//
#include <hip/hip_runtime.h>
#include <hip/hip_bf16.h>
#include <math.h>

// Problem constants
#define BB 2
#define HH 64
#define WW 64
#define CC 128
#define NHD 4
#define HD 32
#define KS 7
#define KK 49
#define HID 512
#define NT (BB*HH*WW)   // 8192 tokens
#define WTS 196608      // elems (qkv 49152 | proj 16384 | fc1 65536 | fc2 65536)

typedef __attribute__((ext_vector_type(8))) short bf16x8;
typedef __attribute__((ext_vector_type(4))) short bf16x4;
typedef __attribute__((ext_vector_type(4))) float f32x4;

__device__ __forceinline__ short f2bs(float v) {
    __hip_bfloat16 h = __float2bfloat16(v);
    return *reinterpret_cast<short*>(&h);
}

__device__ __forceinline__ f32x4 mfma16(bf16x4 a, bf16x4 b, f32x4 c) {
#if __has_builtin(__builtin_amdgcn_mfma_f32_16x16x16bf16_1k)
    return __builtin_amdgcn_mfma_f32_16x16x16bf16_1k(a, b, c, 0, 0, 0);
#else
    asm("v_mfma_f32_16x16x16_bf16 %0, %1, %2, %0" : "+v"(c) : "v"(a), "v"(b));
    return c;
#endif
}

// ---------------- prep: cast/transpose weights, single copy ---------------------
__global__ void prep_cast(const float* __restrict__ qkv_w, const float* __restrict__ proj_w,
                          const float* __restrict__ fc1_w, const float* __restrict__ fc2_w,
                          __hip_bfloat16* __restrict__ wts) {
    int idx = blockIdx.x * 256 + threadIdx.x;
    const float* W; int K, N, off, base;
    if (idx < 49152)       { W = qkv_w;  K = 128; N = 384; off = idx;          base = 0; }
    else if (idx < 65536)  { W = proj_w; K = 128; N = 128; off = idx - 49152;  base = 49152; }
    else if (idx < 131072) { W = fc1_w;  K = 128; N = 512; off = idx - 65536;  base = 65536; }
    else                   { W = fc2_w;  K = 512; N = 128; off = idx - 131072; base = 131072; }
    int k = off / N, n = off - k * N;
    wts[base + n * K + k] = __float2bfloat16(W[(size_t)k * N + n]);
}

// ---------------- LN1 + QKV GEMM: 32 rows/block, 8 waves (48 cols x M=32) -------
// q,k: token-major [h][tok][32]; v: d-major vbT[h*32+d][tok].
__global__ void __launch_bounds__(512, 2)
qkv_ln_kernel(const float* __restrict__ x, const float* __restrict__ g,
              const float* __restrict__ bta, const __hip_bfloat16* __restrict__ wts,
              const float* __restrict__ qkv_b,
              __hip_bfloat16* __restrict__ qb, __hip_bfloat16* __restrict__ kb,
              __hip_bfloat16* __restrict__ vbT) {
    __shared__ ushort4 ys4[32 * 32];    // 8 KB
    int tid = threadIdx.x;
    int R0 = blockIdx.x * 32;
    const __hip_bfloat16* qkv_wt = wts;

    // --- prefetch: all 12 weight fragments for this wave (hidden under LN1) ---
    int wid = tid >> 6, lane = tid & 63;
    int rowf = lane & 15, kg = lane >> 4;
    int n0 = wid * 48;
    bf16x8 bfr[3][4];
    #pragma unroll
    for (int nf = 0; nf < 3; ++nf) {
        int col = n0 + nf * 16 + rowf;
        #pragma unroll
        for (int t = 0; t < 4; ++t)
            bfr[nf][t] = *(const bf16x8*)(qkv_wt + (size_t)col * CC + t * 32 + kg * 8);
    }

    #pragma unroll
    for (int gg = 0; gg < 2; ++gg) {    // LN1: 32 rows, 32 threads/row
        int row = gg * 16 + (tid >> 5), t32 = tid & 31;
        const float* xr = x + (size_t)(R0 + row) * CC + t32 * 4;
        float4 a0 = *(const float4*)xr;
        float s1 = a0.x + a0.y + a0.z + a0.w;
        float s2 = a0.x*a0.x + a0.y*a0.y + a0.z*a0.z + a0.w*a0.w;
        #pragma unroll
        for (int off = 1; off <= 16; off <<= 1) { s1 += __shfl_xor(s1, off); s2 += __shfl_xor(s2, off); }
        float mean = s1 * (1.0f / CC);
        float var  = s2 * (1.0f / CC) - mean * mean;
        float rstd = rsqrtf(var + 1e-5f);
        float4 g0 = *(const float4*)(g + t32 * 4);
        float4 b0 = *(const float4*)(bta + t32 * 4);
        ushort4 ch;
        ch.x = (unsigned short)f2bs((a0.x - mean) * rstd * g0.x + b0.x);
        ch.y = (unsigned short)f2bs((a0.y - mean) * rstd * g0.y + b0.y);
        ch.z = (unsigned short)f2bs((a0.z - mean) * rstd * g0.z + b0.z);
        ch.w = (unsigned short)f2bs((a0.w - mean) * rstd * g0.w + b0.w);
        int c = t32 >> 1;
        ys4[row * 32 + ((c ^ (row & 15)) << 1) + (t32 & 1)] = ch;
    }
    __syncthreads();

    const bf16x8* ys8 = (const bf16x8*)ys4;
    bf16x8 a2[2][4];
    #pragma unroll
    for (int mt = 0; mt < 2; ++mt) {
        int rr = mt * 16 + rowf;
        #pragma unroll
        for (int t = 0; t < 4; ++t)
            a2[mt][t] = ys8[rr * 16 + ((t * 4 + kg) ^ (rr & 15))];
    }

    f32x4 acc[3][2] = {};
    #pragma unroll
    for (int nf = 0; nf < 3; ++nf)
        #pragma unroll
        for (int t = 0; t < 4; ++t)
            #pragma unroll
            for (int mt = 0; mt < 2; ++mt)
                acc[nf][mt] = __builtin_amdgcn_mfma_f32_16x16x32_bf16(a2[mt][t], bfr[nf][t], acc[nf][mt], 0, 0, 0);

    #pragma unroll
    for (int nf = 0; nf < 3; ++nf) {
        int col = n0 + nf * 16 + rowf;
        int which = col >> 7;           // 0=q,1=k,2=v (wave-uniform)
        int h = (col >> 5) & 3;
        int d = col & 31;
        float bv = qkv_b[col];
        #pragma unroll
        for (int mt = 0; mt < 2; ++mt) {
            if (which == 2) {
                ushort4 u;
                u.x = (unsigned short)f2bs(acc[nf][mt][0] + bv);
                u.y = (unsigned short)f2bs(acc[nf][mt][1] + bv);
                u.z = (unsigned short)f2bs(acc[nf][mt][2] + bv);
                u.w = (unsigned short)f2bs(acc[nf][mt][3] + bv);
                *(ushort4*)(vbT + ((size_t)(h * 32 + d) * NT + R0 + mt * 16 + kg * 4)) = u;
            } else {
                __hip_bfloat16* dst = which == 0 ? qb : kb;
                #pragma unroll
                for (int r = 0; r < 4; ++r)
                    dst[((size_t)h * NT + (R0 + mt * 16 + kg * 4 + r)) * HD + d] = __float2bfloat16(acc[nf][mt][r] + bv);
            }
        }
    }
}

// ---------------- MEGA TAIL: 32 tokens/block, 8 waves, grid 256 ------------------
#define X1P 132          // x1s row stride (f32)
#define H1P 520          // h1s row stride (bf16)
__global__ void __launch_bounds__(512, 2)
mega_tail(const __hip_bfloat16* __restrict__ qb, const __hip_bfloat16* __restrict__ kb,
          const __hip_bfloat16* __restrict__ vbT, const float* __restrict__ rpb,
          const float* __restrict__ x, const __hip_bfloat16* __restrict__ wts,
          const float* __restrict__ proj_b,
          const float* __restrict__ n2g, const float* __restrict__ n2b,
          const float* __restrict__ fc1_b, const float* __restrict__ fc2_b,
          float* __restrict__ out) {
    __shared__ float rpbs[720];         // 16-pad + 4*169; pre-scaled by log2e
    __shared__ ushort4 ysA4[32 * 32];   // 8 KB: attn out, reused for LN2 out
    __shared__ float x1s[32 * X1P];     // 16.9 KB
    __shared__ short h1s[32 * H1P];     // 33.3 KB
    int tid = threadIdx.x;
    int R0 = blockIdx.x * 32;
    int wid = tid >> 6, lane = tid & 63;
    int rowf = lane & 15, kg = lane >> 4;
    const __hip_bfloat16* proj_wt = wts + 49152;
    const __hip_bfloat16* fc1_wt  = wts + 65536;
    const __hip_bfloat16* fc2_wt  = wts + 131072;

    // --- prefetch (hidden under attention): proj W, FC1 nf=0, FC2 kc=0, x resid -
    int colB = wid * 16 + rowf;
    bf16x8 pw[4], f2w0[4], f1w0[4];
    float xr0[2][4];
    #pragma unroll
    for (int t = 0; t < 4; ++t) {
        pw[t]   = *(const bf16x8*)(proj_wt + (size_t)colB * CC + t * 32 + kg * 8);
        f2w0[t] = *(const bf16x8*)(fc2_wt + (size_t)colB * HID + t * 32 + kg * 8);
        f1w0[t] = *(const bf16x8*)(fc1_wt + (size_t)(wid * 64 + rowf) * CC + t * 32 + kg * 8);
    }
    #pragma unroll
    for (int mt = 0; mt < 2; ++mt)
        #pragma unroll
        for (int r = 0; r < 4; ++r)
            xr0[mt][r] = x[(size_t)(R0 + mt * 16 + kg * 4 + r) * CC + colB];

    for (int idx = tid; idx < NHD * 169; idx += 512)
        rpbs[16 + idx] = rpb[idx] * 1.4426950408889634f;
    __syncthreads();

    // ---- Phase A: MFMA attention; wave = (head h, q-group qg) ------------------
    {
        const int h  = wid & 3;
        const int qg = wid >> 2;
        const int R0g = R0 + qg * 16;
        const int q = rowf;
        int j0 = R0g & 63;
        int i  = (R0g >> 6) & 63;
        int b  = R0g >> 12;
        int si = i - 3; si = si < 0 ? 0 : (si > 57 ? 57 : si);
        int sjm = j0 - 3; sjm = sjm < 0 ? 0 : (sjm > 57 ? 57 : sjm);
        sjm &= ~1;                      // even for 8B-aligned vbT loads
        int oi = si - i + 6;
        int jq = j0 + q;
        int sjq = jq - 3; sjq = sjq < 0 ? 0 : (sjq > 57 ? 57 : sjq);
        int lo = sjq - sjm;
        int ojq = sjm - jq + 6;
        int rb0 = (b * 64 + si) * 64;

        bf16x8 qf = *(const bf16x8*)(qb + ((size_t)h * NT + R0g + q) * HD + kg * 8);
        const __hip_bfloat16* kb_h = kb + (size_t)h * NT * HD;

        // S^T = K·Q^T : 14 tiles (7 window rows x 2 col-tiles)
        f32x4 s[14];
        #pragma unroll
        for (int kt = 0; kt < 14; ++kt) {
            const int a = kt >> 1;
            const int cb = (kt & 1) * 16;
            int col = q + cb + sjm; col = col > 63 ? 63 : col;
            int tok = rb0 + a * 64 + col;
            bf16x8 kf = *(const bf16x8*)(kb_h + (size_t)tok * HD + kg * 8);
            f32x4 z = {0.f, 0.f, 0.f, 0.f};
            s[kt] = __builtin_amdgcn_mfma_f32_16x16x32_bf16(kf, qf, z, 0, 0, 0);
        }
        // mask + bias (log2-domain) + row max
        const float* rb_h = rpbs + 16 + h * 169 + oi * 13;
        float m = -1e30f;
        #pragma unroll
        for (int kt = 0; kt < 14; ++kt) {
            const int a = kt >> 1;
            const int cb = (kt & 1) * 16;
            const float* bp = rb_h + a * 13 + (ojq + cb + kg * 4);
            #pragma unroll
            for (int r = 0; r < 4; ++r) {
                int c = cb + kg * 4 + r;
                bool valid = (unsigned)(c - lo) < 7u;
                float z = s[kt][r] * 0.25506948f + bp[r];   // (1/sqrt32)*log2e
                s[kt][r] = valid ? z : -1e30f;
                m = fmaxf(m, s[kt][r]);
            }
        }
        m = fmaxf(m, __shfl_xor(m, 16));
        m = fmaxf(m, __shfl_xor(m, 32));

        // P = exp2(S-m); O^T = V^T·P^T (zero-shuffle, P lane-local)
        float l = 0.0f;
        f32x4 o0 = {0.f,0.f,0.f,0.f}, o1 = {0.f,0.f,0.f,0.f};
        const __hip_bfloat16* vt_l = vbT + ((size_t)(h * 32) + q) * NT;
        #pragma unroll
        for (int kt = 0; kt < 14; ++kt) {
            const int a = kt >> 1;
            const int cb = (kt & 1) * 16;
            bf16x4 pb;
            #pragma unroll
            for (int r = 0; r < 4; ++r) {
                float pv = exp2f(s[kt][r] - m);
                l += pv;
                pb[r] = f2bs(pv);
            }
            int colb = cb + kg * 4 + sjm; colb = colb > 60 ? 60 : colb;
            int tokb = rb0 + a * 64 + colb;
            bf16x4 v0 = *(const bf16x4*)(vt_l + tokb);
            bf16x4 v1 = *(const bf16x4*)(vt_l + (size_t)16 * NT + tokb);
            o0 = mfma16(v0, pb, o0);
            o1 = mfma16(v1, pb, o1);
        }
        l += __shfl_xor(l, 16);
        l += __shfl_xor(l, 32);
        float inv = 1.0f / l;

        int lt = qg * 16 + q;
        #pragma unroll
        for (int mt = 0; mt < 2; ++mt) {
            f32x4 ov = mt ? o1 : o0;
            ushort4 u4;
            u4.x = (unsigned short)f2bs(ov[0] * inv);
            u4.y = (unsigned short)f2bs(ov[1] * inv);
            u4.z = (unsigned short)f2bs(ov[2] * inv);
            u4.w = (unsigned short)f2bs(ov[3] * inv);
            int cch = h * 4 + mt * 2 + (kg >> 1);
            ysA4[lt * 32 + ((cch ^ q) << 1) + (kg & 1)] = u4;
        }
    }
    __syncthreads();

    // ---- Phase B: proj (wave w covers 16 cols, M=32), prefetched weights -------
    {
        const bf16x8* ysA8 = (const bf16x8*)ysA4;
        bf16x8 a2[2][4];
        #pragma unroll
        for (int mt = 0; mt < 2; ++mt) {
            int rr = mt * 16 + rowf;
            #pragma unroll
            for (int t = 0; t < 4; ++t)
                a2[mt][t] = ysA8[rr * 16 + ((t * 4 + kg) ^ (rr & 15))];
        }
        f32x4 acc[2] = {};
        #pragma unroll
        for (int t = 0; t < 4; ++t)
            #pragma unroll
            for (int mt = 0; mt < 2; ++mt)
                acc[mt] = __builtin_amdgcn_mfma_f32_16x16x32_bf16(a2[mt][t], pw[t], acc[mt], 0, 0, 0);
        float bv = proj_b[colB];
        #pragma unroll
        for (int mt = 0; mt < 2; ++mt)
            #pragma unroll
            for (int r = 0; r < 4; ++r) {
                int row = mt * 16 + kg * 4 + r;
                x1s[row * X1P + colB] = acc[mt][r] + bv + xr0[mt][r];
            }
    }
    __syncthreads();

    // ---- Phase C: LN2 (32 rows, 2 iterations) -> ysA4 (reused) -----------------
    #pragma unroll
    for (int gg = 0; gg < 2; ++gg) {
        int row = gg * 16 + (tid >> 5), t32 = tid & 31;
        float4 a0 = *(const float4*)&x1s[row * X1P + t32 * 4];
        float s1 = a0.x + a0.y + a0.z + a0.w;
        float s2 = a0.x*a0.x + a0.y*a0.y + a0.z*a0.z + a0.w*a0.w;
        #pragma unroll
        for (int off = 1; off <= 16; off <<= 1) { s1 += __shfl_xor(s1, off); s2 += __shfl_xor(s2, off); }
        float mean = s1 * (1.0f / CC);
        float var  = s2 * (1.0f / CC) - mean * mean;
        float rstd = rsqrtf(var + 1e-5f);
        float4 g0 = *(const float4*)(n2g + t32 * 4);
        float4 b0 = *(const float4*)(n2b + t32 * 4);
        ushort4 ch;
        ch.x = (unsigned short)f2bs((a0.x - mean) * rstd * g0.x + b0.x);
        ch.y = (unsigned short)f2bs((a0.y - mean) * rstd * g0.y + b0.y);
        ch.z = (unsigned short)f2bs((a0.z - mean) * rstd * g0.z + b0.z);
        ch.w = (unsigned short)f2bs((a0.w - mean) * rstd * g0.w + b0.w);
        int c = t32 >> 1;
        ysA4[row * 32 + ((c ^ (row & 15)) << 1) + (t32 & 1)] = ch;
    }
    __syncthreads();

    // ---- Phase D: FC1 + gelu (wave w covers 64 cols, M=32) ---------------------
    {
        const bf16x8* ys8 = (const bf16x8*)ysA4;
        bf16x8 a2[2][4];
        #pragma unroll
        for (int mt = 0; mt < 2; ++mt) {
            int rr = mt * 16 + rowf;
            #pragma unroll
            for (int t = 0; t < 4; ++t)
                a2[mt][t] = ys8[rr * 16 + ((t * 4 + kg) ^ (rr & 15))];
        }
        int n0 = wid * 64;
        f32x4 acc[4][2] = {};
        #pragma unroll
        for (int nf = 0; nf < 4; ++nf) {
            int col = n0 + nf * 16 + rowf;
            bf16x8 bfr[4];
            #pragma unroll
            for (int t = 0; t < 4; ++t)
                bfr[t] = (nf == 0) ? f1w0[t]
                       : *(const bf16x8*)(fc1_wt + (size_t)col * CC + t * 32 + kg * 8);
            #pragma unroll
            for (int t = 0; t < 4; ++t)
                #pragma unroll
                for (int mt = 0; mt < 2; ++mt)
                    acc[nf][mt] = __builtin_amdgcn_mfma_f32_16x16x32_bf16(a2[mt][t], bfr[t], acc[nf][mt], 0, 0, 0);
        }
        #pragma unroll
        for (int nf = 0; nf < 4; ++nf) {
            int col = n0 + nf * 16 + rowf;
            float bv = fc1_b[col];
            #pragma unroll
            for (int mt = 0; mt < 2; ++mt)
                #pragma unroll
                for (int r = 0; r < 4; ++r) {
                    int row = mt * 16 + kg * 4 + r;
                    float v = acc[nf][mt][r] + bv;
                    v = 0.5f * v * (1.0f + erff(v * 0.70710678118654752f));
                    h1s[row * H1P + col] = f2bs(v);
                }
        }
    }
    __syncthreads();

    // ---- Phase E: FC2 + resid (wave w covers 16 cols, M=32), K=512 from LDS ----
    {
        f32x4 acc[2] = {};
        #pragma unroll
        for (int kc = 0; kc < 512; kc += 128) {
            bf16x8 a2e[2][4], bfr[4];
            #pragma unroll
            for (int mt = 0; mt < 2; ++mt) {
                int rr = mt * 16 + rowf;
                #pragma unroll
                for (int t = 0; t < 4; ++t)
                    a2e[mt][t] = *(const bf16x8*)&h1s[rr * H1P + kc + t * 32 + kg * 8];
            }
            #pragma unroll
            for (int t = 0; t < 4; ++t)
                bfr[t] = (kc == 0) ? f2w0[t]
                       : *(const bf16x8*)(fc2_wt + (size_t)colB * HID + kc + t * 32 + kg * 8);
            #pragma unroll
            for (int t = 0; t < 4; ++t)
                #pragma unroll
                for (int mt = 0; mt < 2; ++mt)
                    acc[mt] = __builtin_amdgcn_mfma_f32_16x16x32_bf16(a2e[mt][t], bfr[t], acc[mt], 0, 0, 0);
        }
        float bv = fc2_b[colB];
        #pragma unroll
        for (int mt = 0; mt < 2; ++mt)
            #pragma unroll
            for (int r = 0; r < 4; ++r) {
                int row = mt * 16 + kg * 4 + r;
                out[(size_t)(R0 + row) * CC + colB] = acc[mt][r] + bv + x1s[row * X1P + colB];
            }
    }
}

extern "C" void kernel_launch(void* const* d_in, const int* in_sizes, int n_in,
                              void* d_out, int out_size, void* d_ws, size_t ws_size,
                              hipStream_t stream) {
    const float* x       = (const float*)d_in[0];
    const float* norm1_g = (const float*)d_in[1];
    const float* norm1_b = (const float*)d_in[2];
    const float* qkv_w   = (const float*)d_in[3];
    const float* qkv_b   = (const float*)d_in[4];
    const float* rpb     = (const float*)d_in[5];
    const float* proj_w  = (const float*)d_in[6];
    const float* proj_b  = (const float*)d_in[7];
    const float* norm2_g = (const float*)d_in[8];
    const float* norm2_b = (const float*)d_in[9];
    const float* fc1_w   = (const float*)d_in[10];
    const float* fc1_b   = (const float*)d_in[11];
    const float* fc2_w   = (const float*)d_in[12];
    const float* fc2_b   = (const float*)d_in[13];
    float* out = (float*)d_out;
    char* ws = (char*)d_ws;

    // workspace: qb [4][8192][32], kb, vbT [128][8192] (2MB each); wts single copy
    __hip_bfloat16* qb  = (__hip_bfloat16*)(ws);
    __hip_bfloat16* kb  = (__hip_bfloat16*)(ws + 2097152);
    __hip_bfloat16* vbT = (__hip_bfloat16*)(ws + 4194304);
    __hip_bfloat16* wts = (__hip_bfloat16*)(ws + 6291456);  // 196608 bf16 = 384 KB

    prep_cast<<<768, 256, 0, stream>>>(qkv_w, proj_w, fc1_w, fc2_w, wts);
    qkv_ln_kernel<<<NT / 32, 512, 0, stream>>>(x, norm1_g, norm1_b, wts, qkv_b,
                                               qb, kb, vbT);
    mega_tail<<<NT / 32, 512, 0, stream>>>(qb, kb, vbT, rpb, x, wts, proj_b,
                                           norm2_g, norm2_b, fc1_b, fc2_b, out);
}

// Round 18
// 40.167 us; speedup vs baseline: 1.4990x; 1.0769x over previous
//
#include <hip/hip_runtime.h>
#include <hip/hip_bf16.h>
#include <math.h>

// Problem constants
#define BB 2
#define HH 64
#define WW 64
#define CC 128
#define NHD 4
#define HD 32
#define KS 7
#define KK 49
#define HID 512
#define NT (BB*HH*WW)   // 8192 tokens
#define WTS 196608      // elems (qkv 49152 | proj 16384 | fc1 65536 | fc2 65536)

typedef __attribute__((ext_vector_type(8))) short bf16x8;
typedef __attribute__((ext_vector_type(4))) short bf16x4;
typedef __attribute__((ext_vector_type(4))) float f32x4;

__device__ __forceinline__ short f2bs(float v) {
    __hip_bfloat16 h = __float2bfloat16(v);
    return *reinterpret_cast<short*>(&h);
}

__device__ __forceinline__ f32x4 mfma16(bf16x4 a, bf16x4 b, f32x4 c) {
#if __has_builtin(__builtin_amdgcn_mfma_f32_16x16x16bf16_1k)
    return __builtin_amdgcn_mfma_f32_16x16x16bf16_1k(a, b, c, 0, 0, 0);
#else
    asm("v_mfma_f32_16x16x16_bf16 %0, %1, %2, %0" : "+v"(c) : "v"(a), "v"(b));
    return c;
#endif
}

// ---------------- LN1 + QKV GEMM (+ distributed weight cast for mega_tail) ------
// 32 rows/block, 8 waves (48 cols x M=32). qkv weights cast in-register from f32.
// q,k: token-major [h][tok][32]; v: d-major vbT[h*32+d][tok].
__global__ void __launch_bounds__(512, 2)
qkv_ln_kernel(const float* __restrict__ x, const float* __restrict__ g,
              const float* __restrict__ bta, const float* __restrict__ qkv_w,
              const float* __restrict__ proj_w, const float* __restrict__ fc1_w,
              const float* __restrict__ fc2_w, __hip_bfloat16* __restrict__ wts,
              const float* __restrict__ qkv_b,
              __hip_bfloat16* __restrict__ qb, __hip_bfloat16* __restrict__ kb,
              __hip_bfloat16* __restrict__ vbT) {
    __shared__ ushort4 ys4[32 * 32];    // 8 KB
    int tid = threadIdx.x;
    int R0 = blockIdx.x * 32;

    int wid = tid >> 6, lane = tid & 63;
    int rowf = lane & 15, kg = lane >> 4;
    int n0 = wid * 48;

    // --- in-register cast of this wave's 12 qkv weight fragments (f32 source) ---
    bf16x8 bfr[3][4];
    #pragma unroll
    for (int nf = 0; nf < 3; ++nf) {
        int col = n0 + nf * 16 + rowf;
        #pragma unroll
        for (int t = 0; t < 4; ++t) {
            int k0 = t * 32 + kg * 8;
            bf16x8 f;
            #pragma unroll
            for (int e = 0; e < 8; ++e)
                f[e] = f2bs(qkv_w[(size_t)(k0 + e) * 384 + col]);
            bfr[nf][t] = f;
        }
    }

    // --- distributed cast of proj/fc1/fc2 weights into wts (576 elems/block) ----
    for (int ii = tid; ii < 576; ii += 512) {
        int idx = 49152 + blockIdx.x * 576 + ii;
        const float* W; int K, N, off, base;
        if (idx < 65536)       { W = proj_w; K = 128; N = 128; off = idx - 49152;  base = 49152; }
        else if (idx < 131072) { W = fc1_w;  K = 128; N = 512; off = idx - 65536;  base = 65536; }
        else                   { W = fc2_w;  K = 512; N = 128; off = idx - 131072; base = 131072; }
        int k = off / N, n = off - k * N;
        wts[base + n * K + k] = __float2bfloat16(W[(size_t)k * N + n]);
    }

    #pragma unroll
    for (int gg = 0; gg < 2; ++gg) {    // LN1: 32 rows, 32 threads/row
        int row = gg * 16 + (tid >> 5), t32 = tid & 31;
        const float* xr = x + (size_t)(R0 + row) * CC + t32 * 4;
        float4 a0 = *(const float4*)xr;
        float s1 = a0.x + a0.y + a0.z + a0.w;
        float s2 = a0.x*a0.x + a0.y*a0.y + a0.z*a0.z + a0.w*a0.w;
        #pragma unroll
        for (int off = 1; off <= 16; off <<= 1) { s1 += __shfl_xor(s1, off); s2 += __shfl_xor(s2, off); }
        float mean = s1 * (1.0f / CC);
        float var  = s2 * (1.0f / CC) - mean * mean;
        float rstd = rsqrtf(var + 1e-5f);
        float4 g0 = *(const float4*)(g + t32 * 4);
        float4 b0 = *(const float4*)(bta + t32 * 4);
        ushort4 ch;
        ch.x = (unsigned short)f2bs((a0.x - mean) * rstd * g0.x + b0.x);
        ch.y = (unsigned short)f2bs((a0.y - mean) * rstd * g0.y + b0.y);
        ch.z = (unsigned short)f2bs((a0.z - mean) * rstd * g0.z + b0.z);
        ch.w = (unsigned short)f2bs((a0.w - mean) * rstd * g0.w + b0.w);
        int c = t32 >> 1;
        ys4[row * 32 + ((c ^ (row & 15)) << 1) + (t32 & 1)] = ch;
    }
    __syncthreads();

    const bf16x8* ys8 = (const bf16x8*)ys4;
    bf16x8 a2[2][4];
    #pragma unroll
    for (int mt = 0; mt < 2; ++mt) {
        int rr = mt * 16 + rowf;
        #pragma unroll
        for (int t = 0; t < 4; ++t)
            a2[mt][t] = ys8[rr * 16 + ((t * 4 + kg) ^ (rr & 15))];
    }

    f32x4 acc[3][2] = {};
    #pragma unroll
    for (int nf = 0; nf < 3; ++nf)
        #pragma unroll
        for (int t = 0; t < 4; ++t)
            #pragma unroll
            for (int mt = 0; mt < 2; ++mt)
                acc[nf][mt] = __builtin_amdgcn_mfma_f32_16x16x32_bf16(a2[mt][t], bfr[nf][t], acc[nf][mt], 0, 0, 0);

    #pragma unroll
    for (int nf = 0; nf < 3; ++nf) {
        int col = n0 + nf * 16 + rowf;
        int which = col >> 7;           // 0=q,1=k,2=v (wave-uniform)
        int h = (col >> 5) & 3;
        int d = col & 31;
        float bv = qkv_b[col];
        #pragma unroll
        for (int mt = 0; mt < 2; ++mt) {
            if (which == 2) {
                ushort4 u;
                u.x = (unsigned short)f2bs(acc[nf][mt][0] + bv);
                u.y = (unsigned short)f2bs(acc[nf][mt][1] + bv);
                u.z = (unsigned short)f2bs(acc[nf][mt][2] + bv);
                u.w = (unsigned short)f2bs(acc[nf][mt][3] + bv);
                *(ushort4*)(vbT + ((size_t)(h * 32 + d) * NT + R0 + mt * 16 + kg * 4)) = u;
            } else {
                __hip_bfloat16* dst = which == 0 ? qb : kb;
                #pragma unroll
                for (int r = 0; r < 4; ++r)
                    dst[((size_t)h * NT + (R0 + mt * 16 + kg * 4 + r)) * HD + d] = __float2bfloat16(acc[nf][mt][r] + bv);
            }
        }
    }
}

// ---------------- MEGA TAIL: 32 tokens/block, 8 waves, grid 256 ------------------
#define X1P 132          // x1s row stride (f32)
#define H1P 520          // h1s row stride (bf16)
__global__ void __launch_bounds__(512, 2)
mega_tail(const __hip_bfloat16* __restrict__ qb, const __hip_bfloat16* __restrict__ kb,
          const __hip_bfloat16* __restrict__ vbT, const float* __restrict__ rpb,
          const float* __restrict__ x, const __hip_bfloat16* __restrict__ wts,
          const float* __restrict__ proj_b,
          const float* __restrict__ n2g, const float* __restrict__ n2b,
          const float* __restrict__ fc1_b, const float* __restrict__ fc2_b,
          float* __restrict__ out) {
    __shared__ float rpbs[720];         // 16-pad + 4*169; pre-scaled by log2e
    __shared__ ushort4 ysA4[32 * 32];   // 8 KB: attn out, reused for LN2 out
    __shared__ float x1s[32 * X1P];     // 16.9 KB
    __shared__ short h1s[32 * H1P];     // 33.3 KB
    int tid = threadIdx.x;
    int R0 = blockIdx.x * 32;
    int wid = tid >> 6, lane = tid & 63;
    int rowf = lane & 15, kg = lane >> 4;
    const __hip_bfloat16* proj_wt = wts + 49152;
    const __hip_bfloat16* fc1_wt  = wts + 65536;
    const __hip_bfloat16* fc2_wt  = wts + 131072;

    // --- prefetch (hidden under attention): proj W, FC1 nf=0, FC2 kc=0, x resid -
    int colB = wid * 16 + rowf;
    bf16x8 pw[4], f2w0[4], f1w0[4];
    float xr0[2][4];
    #pragma unroll
    for (int t = 0; t < 4; ++t) {
        pw[t]   = *(const bf16x8*)(proj_wt + (size_t)colB * CC + t * 32 + kg * 8);
        f2w0[t] = *(const bf16x8*)(fc2_wt + (size_t)colB * HID + t * 32 + kg * 8);
        f1w0[t] = *(const bf16x8*)(fc1_wt + (size_t)(wid * 64 + rowf) * CC + t * 32 + kg * 8);
    }
    #pragma unroll
    for (int mt = 0; mt < 2; ++mt)
        #pragma unroll
        for (int r = 0; r < 4; ++r)
            xr0[mt][r] = x[(size_t)(R0 + mt * 16 + kg * 4 + r) * CC + colB];

    for (int idx = tid; idx < NHD * 169; idx += 512)
        rpbs[16 + idx] = rpb[idx] * 1.4426950408889634f;
    __syncthreads();

    // ---- Phase A: MFMA attention; wave = (head h, q-group qg) ------------------
    {
        const int h  = wid & 3;
        const int qg = wid >> 2;
        const int R0g = R0 + qg * 16;
        const int q = rowf;
        int j0 = R0g & 63;
        int i  = (R0g >> 6) & 63;
        int b  = R0g >> 12;
        int si = i - 3; si = si < 0 ? 0 : (si > 57 ? 57 : si);
        int sjm = j0 - 3; sjm = sjm < 0 ? 0 : (sjm > 57 ? 57 : sjm);
        sjm &= ~1;                      // even for 8B-aligned vbT loads
        int oi = si - i + 6;
        int jq = j0 + q;
        int sjq = jq - 3; sjq = sjq < 0 ? 0 : (sjq > 57 ? 57 : sjq);
        int lo = sjq - sjm;
        int ojq = sjm - jq + 6;
        int rb0 = (b * 64 + si) * 64;

        bf16x8 qf = *(const bf16x8*)(qb + ((size_t)h * NT + R0g + q) * HD + kg * 8);
        const __hip_bfloat16* kb_h = kb + (size_t)h * NT * HD;

        // S^T = K·Q^T : 14 tiles (7 window rows x 2 col-tiles)
        f32x4 s[14];
        #pragma unroll
        for (int kt = 0; kt < 14; ++kt) {
            const int a = kt >> 1;
            const int cb = (kt & 1) * 16;
            int col = q + cb + sjm; col = col > 63 ? 63 : col;
            int tok = rb0 + a * 64 + col;
            bf16x8 kf = *(const bf16x8*)(kb_h + (size_t)tok * HD + kg * 8);
            f32x4 z = {0.f, 0.f, 0.f, 0.f};
            s[kt] = __builtin_amdgcn_mfma_f32_16x16x32_bf16(kf, qf, z, 0, 0, 0);
        }
        // mask + bias (log2-domain) + row max
        const float* rb_h = rpbs + 16 + h * 169 + oi * 13;
        float m = -1e30f;
        #pragma unroll
        for (int kt = 0; kt < 14; ++kt) {
            const int a = kt >> 1;
            const int cb = (kt & 1) * 16;
            const float* bp = rb_h + a * 13 + (ojq + cb + kg * 4);
            #pragma unroll
            for (int r = 0; r < 4; ++r) {
                int c = cb + kg * 4 + r;
                bool valid = (unsigned)(c - lo) < 7u;
                float z = s[kt][r] * 0.25506948f + bp[r];   // (1/sqrt32)*log2e
                s[kt][r] = valid ? z : -1e30f;
                m = fmaxf(m, s[kt][r]);
            }
        }
        m = fmaxf(m, __shfl_xor(m, 16));
        m = fmaxf(m, __shfl_xor(m, 32));

        // P = exp2(S-m); O^T = V^T·P^T (zero-shuffle, P lane-local)
        float l = 0.0f;
        f32x4 o0 = {0.f,0.f,0.f,0.f}, o1 = {0.f,0.f,0.f,0.f};
        const __hip_bfloat16* vt_l = vbT + ((size_t)(h * 32) + q) * NT;
        #pragma unroll
        for (int kt = 0; kt < 14; ++kt) {
            const int a = kt >> 1;
            const int cb = (kt & 1) * 16;
            bf16x4 pb;
            #pragma unroll
            for (int r = 0; r < 4; ++r) {
                float pv = exp2f(s[kt][r] - m);
                l += pv;
                pb[r] = f2bs(pv);
            }
            int colb = cb + kg * 4 + sjm; colb = colb > 60 ? 60 : colb;
            int tokb = rb0 + a * 64 + colb;
            bf16x4 v0 = *(const bf16x4*)(vt_l + tokb);
            bf16x4 v1 = *(const bf16x4*)(vt_l + (size_t)16 * NT + tokb);
            o0 = mfma16(v0, pb, o0);
            o1 = mfma16(v1, pb, o1);
        }
        l += __shfl_xor(l, 16);
        l += __shfl_xor(l, 32);
        float inv = 1.0f / l;

        int lt = qg * 16 + q;
        #pragma unroll
        for (int mt = 0; mt < 2; ++mt) {
            f32x4 ov = mt ? o1 : o0;
            ushort4 u4;
            u4.x = (unsigned short)f2bs(ov[0] * inv);
            u4.y = (unsigned short)f2bs(ov[1] * inv);
            u4.z = (unsigned short)f2bs(ov[2] * inv);
            u4.w = (unsigned short)f2bs(ov[3] * inv);
            int cch = h * 4 + mt * 2 + (kg >> 1);
            ysA4[lt * 32 + ((cch ^ q) << 1) + (kg & 1)] = u4;
        }
    }
    __syncthreads();

    // ---- Phase B: proj (wave w covers 16 cols, M=32), prefetched weights -------
    {
        const bf16x8* ysA8 = (const bf16x8*)ysA4;
        bf16x8 a2[2][4];
        #pragma unroll
        for (int mt = 0; mt < 2; ++mt) {
            int rr = mt * 16 + rowf;
            #pragma unroll
            for (int t = 0; t < 4; ++t)
                a2[mt][t] = ysA8[rr * 16 + ((t * 4 + kg) ^ (rr & 15))];
        }
        f32x4 acc[2] = {};
        #pragma unroll
        for (int t = 0; t < 4; ++t)
            #pragma unroll
            for (int mt = 0; mt < 2; ++mt)
                acc[mt] = __builtin_amdgcn_mfma_f32_16x16x32_bf16(a2[mt][t], pw[t], acc[mt], 0, 0, 0);
        float bv = proj_b[colB];
        #pragma unroll
        for (int mt = 0; mt < 2; ++mt)
            #pragma unroll
            for (int r = 0; r < 4; ++r) {
                int row = mt * 16 + kg * 4 + r;
                x1s[row * X1P + colB] = acc[mt][r] + bv + xr0[mt][r];
            }
    }
    __syncthreads();

    // ---- Phase C: LN2 (32 rows, 2 iterations) -> ysA4 (reused) -----------------
    #pragma unroll
    for (int gg = 0; gg < 2; ++gg) {
        int row = gg * 16 + (tid >> 5), t32 = tid & 31;
        float4 a0 = *(const float4*)&x1s[row * X1P + t32 * 4];
        float s1 = a0.x + a0.y + a0.z + a0.w;
        float s2 = a0.x*a0.x + a0.y*a0.y + a0.z*a0.z + a0.w*a0.w;
        #pragma unroll
        for (int off = 1; off <= 16; off <<= 1) { s1 += __shfl_xor(s1, off); s2 += __shfl_xor(s2, off); }
        float mean = s1 * (1.0f / CC);
        float var  = s2 * (1.0f / CC) - mean * mean;
        float rstd = rsqrtf(var + 1e-5f);
        float4 g0 = *(const float4*)(n2g + t32 * 4);
        float4 b0 = *(const float4*)(n2b + t32 * 4);
        ushort4 ch;
        ch.x = (unsigned short)f2bs((a0.x - mean) * rstd * g0.x + b0.x);
        ch.y = (unsigned short)f2bs((a0.y - mean) * rstd * g0.y + b0.y);
        ch.z = (unsigned short)f2bs((a0.z - mean) * rstd * g0.z + b0.z);
        ch.w = (unsigned short)f2bs((a0.w - mean) * rstd * g0.w + b0.w);
        int c = t32 >> 1;
        ysA4[row * 32 + ((c ^ (row & 15)) << 1) + (t32 & 1)] = ch;
    }
    __syncthreads();

    // ---- Phase D: FC1 + gelu (wave w covers 64 cols, M=32) ---------------------
    {
        const bf16x8* ys8 = (const bf16x8*)ysA4;
        bf16x8 a2[2][4];
        #pragma unroll
        for (int mt = 0; mt < 2; ++mt) {
            int rr = mt * 16 + rowf;
            #pragma unroll
            for (int t = 0; t < 4; ++t)
                a2[mt][t] = ys8[rr * 16 + ((t * 4 + kg) ^ (rr & 15))];
        }
        int n0 = wid * 64;
        f32x4 acc[4][2] = {};
        #pragma unroll
        for (int nf = 0; nf < 4; ++nf) {
            int col = n0 + nf * 16 + rowf;
            bf16x8 bfr[4];
            #pragma unroll
            for (int t = 0; t < 4; ++t)
                bfr[t] = (nf == 0) ? f1w0[t]
                       : *(const bf16x8*)(fc1_wt + (size_t)col * CC + t * 32 + kg * 8);
            #pragma unroll
            for (int t = 0; t < 4; ++t)
                #pragma unroll
                for (int mt = 0; mt < 2; ++mt)
                    acc[nf][mt] = __builtin_amdgcn_mfma_f32_16x16x32_bf16(a2[mt][t], bfr[t], acc[nf][mt], 0, 0, 0);
        }
        #pragma unroll
        for (int nf = 0; nf < 4; ++nf) {
            int col = n0 + nf * 16 + rowf;
            float bv = fc1_b[col];
            #pragma unroll
            for (int mt = 0; mt < 2; ++mt)
                #pragma unroll
                for (int r = 0; r < 4; ++r) {
                    int row = mt * 16 + kg * 4 + r;
                    float v = acc[nf][mt][r] + bv;
                    v = 0.5f * v * (1.0f + erff(v * 0.70710678118654752f));
                    h1s[row * H1P + col] = f2bs(v);
                }
        }
    }
    __syncthreads();

    // ---- Phase E: FC2 + resid (wave w covers 16 cols, M=32), K=512 from LDS ----
    {
        f32x4 acc[2] = {};
        #pragma unroll
        for (int kc = 0; kc < 512; kc += 128) {
            bf16x8 a2e[2][4], bfr[4];
            #pragma unroll
            for (int mt = 0; mt < 2; ++mt) {
                int rr = mt * 16 + rowf;
                #pragma unroll
                for (int t = 0; t < 4; ++t)
                    a2e[mt][t] = *(const bf16x8*)&h1s[rr * H1P + kc + t * 32 + kg * 8];
            }
            #pragma unroll
            for (int t = 0; t < 4; ++t)
                bfr[t] = (kc == 0) ? f2w0[t]
                       : *(const bf16x8*)(fc2_wt + (size_t)colB * HID + kc + t * 32 + kg * 8);
            #pragma unroll
            for (int t = 0; t < 4; ++t)
                #pragma unroll
                for (int mt = 0; mt < 2; ++mt)
                    acc[mt] = __builtin_amdgcn_mfma_f32_16x16x32_bf16(a2e[mt][t], bfr[t], acc[mt], 0, 0, 0);
        }
        float bv = fc2_b[colB];
        #pragma unroll
        for (int mt = 0; mt < 2; ++mt)
            #pragma unroll
            for (int r = 0; r < 4; ++r) {
                int row = mt * 16 + kg * 4 + r;
                out[(size_t)(R0 + row) * CC + colB] = acc[mt][r] + bv + x1s[row * X1P + colB];
            }
    }
}

extern "C" void kernel_launch(void* const* d_in, const int* in_sizes, int n_in,
                              void* d_out, int out_size, void* d_ws, size_t ws_size,
                              hipStream_t stream) {
    const float* x       = (const float*)d_in[0];
    const float* norm1_g = (const float*)d_in[1];
    const float* norm1_b = (const float*)d_in[2];
    const float* qkv_w   = (const float*)d_in[3];
    const float* qkv_b   = (const float*)d_in[4];
    const float* rpb     = (const float*)d_in[5];
    const float* proj_w  = (const float*)d_in[6];
    const float* proj_b  = (const float*)d_in[7];
    const float* norm2_g = (const float*)d_in[8];
    const float* norm2_b = (const float*)d_in[9];
    const float* fc1_w   = (const float*)d_in[10];
    const float* fc1_b   = (const float*)d_in[11];
    const float* fc2_w   = (const float*)d_in[12];
    const float* fc2_b   = (const float*)d_in[13];
    float* out = (float*)d_out;
    char* ws = (char*)d_ws;

    // workspace: qb [4][8192][32], kb, vbT [128][8192] (2MB each); wts single copy
    __hip_bfloat16* qb  = (__hip_bfloat16*)(ws);
    __hip_bfloat16* kb  = (__hip_bfloat16*)(ws + 2097152);
    __hip_bfloat16* vbT = (__hip_bfloat16*)(ws + 4194304);
    __hip_bfloat16* wts = (__hip_bfloat16*)(ws + 6291456);  // 196608 bf16 = 384 KB

    qkv_ln_kernel<<<NT / 32, 512, 0, stream>>>(x, norm1_g, norm1_b, qkv_w,
                                               proj_w, fc1_w, fc2_w, wts, qkv_b,
                                               qb, kb, vbT);
    mega_tail<<<NT / 32, 512, 0, stream>>>(qb, kb, vbT, rpb, x, wts, proj_b,
                                           norm2_g, norm2_b, fc1_b, fc2_b, out);
}

// Round 19
// 39.312 us; speedup vs baseline: 1.5316x; 1.0218x over previous
//
#include <hip/hip_runtime.h>
#include <hip/hip_bf16.h>
#include <math.h>

// Problem constants
#define BB 2
#define HH 64
#define WW 64
#define CC 128
#define NHD 4
#define HD 32
#define KS 7
#define KK 49
#define HID 512
#define NT (BB*HH*WW)   // 8192 tokens
#define WTS 196608      // elems (qkv 49152 | proj 16384 | fc1 65536 | fc2 65536)

typedef __attribute__((ext_vector_type(8))) short bf16x8;
typedef __attribute__((ext_vector_type(4))) short bf16x4;
typedef __attribute__((ext_vector_type(4))) float f32x4;

__device__ __forceinline__ short f2bs(float v) {
    __hip_bfloat16 h = __float2bfloat16(v);
    return *reinterpret_cast<short*>(&h);
}

__device__ __forceinline__ f32x4 mfma16(bf16x4 a, bf16x4 b, f32x4 c) {
#if __has_builtin(__builtin_amdgcn_mfma_f32_16x16x16bf16_1k)
    return __builtin_amdgcn_mfma_f32_16x16x16bf16_1k(a, b, c, 0, 0, 0);
#else
    asm("v_mfma_f32_16x16x16_bf16 %0, %1, %2, %0" : "+v"(c) : "v"(a), "v"(b));
    return c;
#endif
}

// ---------------- LN1 + QKV GEMM (+ distributed weight cast for mega_tail) ------
// 32 rows/block, 8 waves (48 cols x M=32). LN1 loads issue FIRST (gate the
// barrier); qkv weight cast + wts cast issue after (consumed post-barrier).
__global__ void __launch_bounds__(512, 2)
qkv_ln_kernel(const float* __restrict__ x, const float* __restrict__ g,
              const float* __restrict__ bta, const float* __restrict__ qkv_w,
              const float* __restrict__ proj_w, const float* __restrict__ fc1_w,
              const float* __restrict__ fc2_w, __hip_bfloat16* __restrict__ wts,
              const float* __restrict__ qkv_b,
              __hip_bfloat16* __restrict__ qb, __hip_bfloat16* __restrict__ kb,
              __hip_bfloat16* __restrict__ vbT) {
    __shared__ ushort4 ys4[32 * 32];    // 8 KB
    int tid = threadIdx.x;
    int R0 = blockIdx.x * 32;

    int wid = tid >> 6, lane = tid & 63;
    int rowf = lane & 15, kg = lane >> 4;
    int n0 = wid * 48;

    // ---- LN1 first: 32 rows, 32 threads/row (its loads gate the barrier) ------
    #pragma unroll
    for (int gg = 0; gg < 2; ++gg) {
        int row = gg * 16 + (tid >> 5), t32 = tid & 31;
        const float* xr = x + (size_t)(R0 + row) * CC + t32 * 4;
        float4 a0 = *(const float4*)xr;
        float s1 = a0.x + a0.y + a0.z + a0.w;
        float s2 = a0.x*a0.x + a0.y*a0.y + a0.z*a0.z + a0.w*a0.w;
        #pragma unroll
        for (int off = 1; off <= 16; off <<= 1) { s1 += __shfl_xor(s1, off); s2 += __shfl_xor(s2, off); }
        float mean = s1 * (1.0f / CC);
        float var  = s2 * (1.0f / CC) - mean * mean;
        float rstd = rsqrtf(var + 1e-5f);
        float4 g0 = *(const float4*)(g + t32 * 4);
        float4 b0 = *(const float4*)(bta + t32 * 4);
        ushort4 ch;
        ch.x = (unsigned short)f2bs((a0.x - mean) * rstd * g0.x + b0.x);
        ch.y = (unsigned short)f2bs((a0.y - mean) * rstd * g0.y + b0.y);
        ch.z = (unsigned short)f2bs((a0.z - mean) * rstd * g0.z + b0.z);
        ch.w = (unsigned short)f2bs((a0.w - mean) * rstd * g0.w + b0.w);
        int c = t32 >> 1;
        ys4[row * 32 + ((c ^ (row & 15)) << 1) + (t32 & 1)] = ch;
    }

    // ---- in-register cast of this wave's 12 qkv weight fragments (post-LN issue)
    bf16x8 bfr[3][4];
    #pragma unroll
    for (int nf = 0; nf < 3; ++nf) {
        int col = n0 + nf * 16 + rowf;
        #pragma unroll
        for (int t = 0; t < 4; ++t) {
            int k0 = t * 32 + kg * 8;
            bf16x8 f;
            #pragma unroll
            for (int e = 0; e < 8; ++e)
                f[e] = f2bs(qkv_w[(size_t)(k0 + e) * 384 + col]);
            bfr[nf][t] = f;
        }
    }

    // ---- distributed cast of proj/fc1/fc2 weights into wts (576 elems/block) ---
    for (int ii = tid; ii < 576; ii += 512) {
        int idx = 49152 + blockIdx.x * 576 + ii;
        const float* W; int K, N, off, base;
        if (idx < 65536)       { W = proj_w; K = 128; N = 128; off = idx - 49152;  base = 49152; }
        else if (idx < 131072) { W = fc1_w;  K = 128; N = 512; off = idx - 65536;  base = 65536; }
        else                   { W = fc2_w;  K = 512; N = 128; off = idx - 131072; base = 131072; }
        int k = off / N, n = off - k * N;
        wts[base + n * K + k] = __float2bfloat16(W[(size_t)k * N + n]);
    }
    __syncthreads();

    const bf16x8* ys8 = (const bf16x8*)ys4;
    bf16x8 a2[2][4];
    #pragma unroll
    for (int mt = 0; mt < 2; ++mt) {
        int rr = mt * 16 + rowf;
        #pragma unroll
        for (int t = 0; t < 4; ++t)
            a2[mt][t] = ys8[rr * 16 + ((t * 4 + kg) ^ (rr & 15))];
    }

    f32x4 acc[3][2] = {};
    #pragma unroll
    for (int nf = 0; nf < 3; ++nf)
        #pragma unroll
        for (int t = 0; t < 4; ++t)
            #pragma unroll
            for (int mt = 0; mt < 2; ++mt)
                acc[nf][mt] = __builtin_amdgcn_mfma_f32_16x16x32_bf16(a2[mt][t], bfr[nf][t], acc[nf][mt], 0, 0, 0);

    #pragma unroll
    for (int nf = 0; nf < 3; ++nf) {
        int col = n0 + nf * 16 + rowf;
        int which = col >> 7;           // 0=q,1=k,2=v (wave-uniform)
        int h = (col >> 5) & 3;
        int d = col & 31;
        float bv = qkv_b[col];
        #pragma unroll
        for (int mt = 0; mt < 2; ++mt) {
            if (which == 2) {
                ushort4 u;
                u.x = (unsigned short)f2bs(acc[nf][mt][0] + bv);
                u.y = (unsigned short)f2bs(acc[nf][mt][1] + bv);
                u.z = (unsigned short)f2bs(acc[nf][mt][2] + bv);
                u.w = (unsigned short)f2bs(acc[nf][mt][3] + bv);
                *(ushort4*)(vbT + ((size_t)(h * 32 + d) * NT + R0 + mt * 16 + kg * 4)) = u;
            } else {
                __hip_bfloat16* dst = which == 0 ? qb : kb;
                #pragma unroll
                for (int r = 0; r < 4; ++r)
                    dst[((size_t)h * NT + (R0 + mt * 16 + kg * 4 + r)) * HD + d] = __float2bfloat16(acc[nf][mt][r] + bv);
            }
        }
    }
}

// ---------------- MEGA TAIL: 32 tokens/block, 8 waves, grid 256 ------------------
#define X1P 132          // x1s row stride (f32)
#define H1P 520          // h1s row stride (bf16)
__global__ void __launch_bounds__(512, 2)
mega_tail(const __hip_bfloat16* __restrict__ qb, const __hip_bfloat16* __restrict__ kb,
          const __hip_bfloat16* __restrict__ vbT, const float* __restrict__ rpb,
          const float* __restrict__ x, const __hip_bfloat16* __restrict__ wts,
          const float* __restrict__ proj_b,
          const float* __restrict__ n2g, const float* __restrict__ n2b,
          const float* __restrict__ fc1_b, const float* __restrict__ fc2_b,
          float* __restrict__ out) {
    __shared__ float rpbs[720];         // 16-pad + 4*169; pre-scaled by log2e
    __shared__ ushort4 ysA4[32 * 32];   // 8 KB: attn out, reused for LN2 out
    __shared__ float x1s[32 * X1P];     // 16.9 KB
    __shared__ short h1s[32 * H1P];     // 33.3 KB
    int tid = threadIdx.x;
    int R0 = blockIdx.x * 32;
    int wid = tid >> 6, lane = tid & 63;
    int rowf = lane & 15, kg = lane >> 4;
    const __hip_bfloat16* proj_wt = wts + 49152;
    const __hip_bfloat16* fc1_wt  = wts + 65536;
    const __hip_bfloat16* fc2_wt  = wts + 131072;

    // ---- rpbs staging FIRST (gates phase A's bias reads) -----------------------
    for (int idx = tid; idx < NHD * 169; idx += 512)
        rpbs[16 + idx] = rpb[idx] * 1.4426950408889634f;

    // ---- attention geometry + qf hoist (qb is from previous kernel) ------------
    const int h  = wid & 3;
    const int qg = wid >> 2;
    const int R0g = R0 + qg * 16;
    const int q = rowf;
    int j0 = R0g & 63;
    int i  = (R0g >> 6) & 63;
    int b  = R0g >> 12;
    int si = i - 3; si = si < 0 ? 0 : (si > 57 ? 57 : si);
    int sjm = j0 - 3; sjm = sjm < 0 ? 0 : (sjm > 57 ? 57 : sjm);
    sjm &= ~1;                      // even for 8B-aligned vbT loads
    int oi = si - i + 6;
    int jq = j0 + q;
    int sjq = jq - 3; sjq = sjq < 0 ? 0 : (sjq > 57 ? 57 : sjq);
    int lo = sjq - sjm;
    int ojq = sjm - jq + 6;
    int rb0 = (b * 64 + si) * 64;
    bf16x8 qf = *(const bf16x8*)(qb + ((size_t)h * NT + R0g + q) * HD + kg * 8);

    // ---- prefetch (consumed phases B/D/E): proj W, FC1 all, FC2 kc=0, x resid --
    int colB = wid * 16 + rowf;
    bf16x8 pw[4], f2w0[4], f1w[4][4];
    float xr0[2][4];
    #pragma unroll
    for (int t = 0; t < 4; ++t) {
        pw[t]   = *(const bf16x8*)(proj_wt + (size_t)colB * CC + t * 32 + kg * 8);
        f2w0[t] = *(const bf16x8*)(fc2_wt + (size_t)colB * HID + t * 32 + kg * 8);
    }
    #pragma unroll
    for (int nf = 0; nf < 4; ++nf) {
        int col = wid * 64 + nf * 16 + rowf;
        #pragma unroll
        for (int t = 0; t < 4; ++t)
            f1w[nf][t] = *(const bf16x8*)(fc1_wt + (size_t)col * CC + t * 32 + kg * 8);
    }
    #pragma unroll
    for (int mt = 0; mt < 2; ++mt)
        #pragma unroll
        for (int r = 0; r < 4; ++r)
            xr0[mt][r] = x[(size_t)(R0 + mt * 16 + kg * 4 + r) * CC + colB];

    __syncthreads();

    // ---- Phase A: MFMA attention; wave = (head h, q-group qg) ------------------
    {
        const __hip_bfloat16* kb_h = kb + (size_t)h * NT * HD;

        // S^T = K·Q^T : 14 tiles (7 window rows x 2 col-tiles)
        f32x4 s[14];
        #pragma unroll
        for (int kt = 0; kt < 14; ++kt) {
            const int a = kt >> 1;
            const int cb = (kt & 1) * 16;
            int col = q + cb + sjm; col = col > 63 ? 63 : col;
            int tok = rb0 + a * 64 + col;
            bf16x8 kf = *(const bf16x8*)(kb_h + (size_t)tok * HD + kg * 8);
            f32x4 z = {0.f, 0.f, 0.f, 0.f};
            s[kt] = __builtin_amdgcn_mfma_f32_16x16x32_bf16(kf, qf, z, 0, 0, 0);
        }
        // mask + bias (log2-domain) + row max
        const float* rb_h = rpbs + 16 + h * 169 + oi * 13;
        float m = -1e30f;
        #pragma unroll
        for (int kt = 0; kt < 14; ++kt) {
            const int a = kt >> 1;
            const int cb = (kt & 1) * 16;
            const float* bp = rb_h + a * 13 + (ojq + cb + kg * 4);
            #pragma unroll
            for (int r = 0; r < 4; ++r) {
                int c = cb + kg * 4 + r;
                bool valid = (unsigned)(c - lo) < 7u;
                float z = s[kt][r] * 0.25506948f + bp[r];   // (1/sqrt32)*log2e
                s[kt][r] = valid ? z : -1e30f;
                m = fmaxf(m, s[kt][r]);
            }
        }
        m = fmaxf(m, __shfl_xor(m, 16));
        m = fmaxf(m, __shfl_xor(m, 32));

        // P = exp2(S-m); O^T = V^T·P^T (zero-shuffle, P lane-local)
        float l = 0.0f;
        f32x4 o0 = {0.f,0.f,0.f,0.f}, o1 = {0.f,0.f,0.f,0.f};
        const __hip_bfloat16* vt_l = vbT + ((size_t)(h * 32) + q) * NT;
        #pragma unroll
        for (int kt = 0; kt < 14; ++kt) {
            const int a = kt >> 1;
            const int cb = (kt & 1) * 16;
            bf16x4 pb;
            #pragma unroll
            for (int r = 0; r < 4; ++r) {
                float pv = exp2f(s[kt][r] - m);
                l += pv;
                pb[r] = f2bs(pv);
            }
            int colb = cb + kg * 4 + sjm; colb = colb > 60 ? 60 : colb;
            int tokb = rb0 + a * 64 + colb;
            bf16x4 v0 = *(const bf16x4*)(vt_l + tokb);
            bf16x4 v1 = *(const bf16x4*)(vt_l + (size_t)16 * NT + tokb);
            o0 = mfma16(v0, pb, o0);
            o1 = mfma16(v1, pb, o1);
        }
        l += __shfl_xor(l, 16);
        l += __shfl_xor(l, 32);
        float inv = 1.0f / l;

        int lt = qg * 16 + q;
        #pragma unroll
        for (int mt = 0; mt < 2; ++mt) {
            f32x4 ov = mt ? o1 : o0;
            ushort4 u4;
            u4.x = (unsigned short)f2bs(ov[0] * inv);
            u4.y = (unsigned short)f2bs(ov[1] * inv);
            u4.z = (unsigned short)f2bs(ov[2] * inv);
            u4.w = (unsigned short)f2bs(ov[3] * inv);
            int cch = h * 4 + mt * 2 + (kg >> 1);
            ysA4[lt * 32 + ((cch ^ q) << 1) + (kg & 1)] = u4;
        }
    }
    __syncthreads();

    // ---- Phase B: proj (wave w covers 16 cols, M=32), prefetched weights -------
    {
        const bf16x8* ysA8 = (const bf16x8*)ysA4;
        bf16x8 a2[2][4];
        #pragma unroll
        for (int mt = 0; mt < 2; ++mt) {
            int rr = mt * 16 + rowf;
            #pragma unroll
            for (int t = 0; t < 4; ++t)
                a2[mt][t] = ysA8[rr * 16 + ((t * 4 + kg) ^ (rr & 15))];
        }
        f32x4 acc[2] = {};
        #pragma unroll
        for (int t = 0; t < 4; ++t)
            #pragma unroll
            for (int mt = 0; mt < 2; ++mt)
                acc[mt] = __builtin_amdgcn_mfma_f32_16x16x32_bf16(a2[mt][t], pw[t], acc[mt], 0, 0, 0);
        float bv = proj_b[colB];
        #pragma unroll
        for (int mt = 0; mt < 2; ++mt)
            #pragma unroll
            for (int r = 0; r < 4; ++r) {
                int row = mt * 16 + kg * 4 + r;
                x1s[row * X1P + colB] = acc[mt][r] + bv + xr0[mt][r];
            }
    }
    __syncthreads();

    // ---- Phase C: LN2 (32 rows, 2 iterations) -> ysA4 (reused) -----------------
    #pragma unroll
    for (int gg = 0; gg < 2; ++gg) {
        int row = gg * 16 + (tid >> 5), t32 = tid & 31;
        float4 a0 = *(const float4*)&x1s[row * X1P + t32 * 4];
        float s1 = a0.x + a0.y + a0.z + a0.w;
        float s2 = a0.x*a0.x + a0.y*a0.y + a0.z*a0.z + a0.w*a0.w;
        #pragma unroll
        for (int off = 1; off <= 16; off <<= 1) { s1 += __shfl_xor(s1, off); s2 += __shfl_xor(s2, off); }
        float mean = s1 * (1.0f / CC);
        float var  = s2 * (1.0f / CC) - mean * mean;
        float rstd = rsqrtf(var + 1e-5f);
        float4 g0 = *(const float4*)(n2g + t32 * 4);
        float4 b0 = *(const float4*)(n2b + t32 * 4);
        ushort4 ch;
        ch.x = (unsigned short)f2bs((a0.x - mean) * rstd * g0.x + b0.x);
        ch.y = (unsigned short)f2bs((a0.y - mean) * rstd * g0.y + b0.y);
        ch.z = (unsigned short)f2bs((a0.z - mean) * rstd * g0.z + b0.z);
        ch.w = (unsigned short)f2bs((a0.w - mean) * rstd * g0.w + b0.w);
        int c = t32 >> 1;
        ysA4[row * 32 + ((c ^ (row & 15)) << 1) + (t32 & 1)] = ch;
    }
    __syncthreads();

    // ---- Phase D: FC1 + gelu (wave w covers 64 cols, M=32), prefetched ---------
    {
        const bf16x8* ys8 = (const bf16x8*)ysA4;
        bf16x8 a2[2][4];
        #pragma unroll
        for (int mt = 0; mt < 2; ++mt) {
            int rr = mt * 16 + rowf;
            #pragma unroll
            for (int t = 0; t < 4; ++t)
                a2[mt][t] = ys8[rr * 16 + ((t * 4 + kg) ^ (rr & 15))];
        }
        int n0 = wid * 64;
        f32x4 acc[4][2] = {};
        #pragma unroll
        for (int nf = 0; nf < 4; ++nf)
            #pragma unroll
            for (int t = 0; t < 4; ++t)
                #pragma unroll
                for (int mt = 0; mt < 2; ++mt)
                    acc[nf][mt] = __builtin_amdgcn_mfma_f32_16x16x32_bf16(a2[mt][t], f1w[nf][t], acc[nf][mt], 0, 0, 0);
        #pragma unroll
        for (int nf = 0; nf < 4; ++nf) {
            int col = n0 + nf * 16 + rowf;
            float bv = fc1_b[col];
            #pragma unroll
            for (int mt = 0; mt < 2; ++mt)
                #pragma unroll
                for (int r = 0; r < 4; ++r) {
                    int row = mt * 16 + kg * 4 + r;
                    float v = acc[nf][mt][r] + bv;
                    v = 0.5f * v * (1.0f + erff(v * 0.70710678118654752f));
                    h1s[row * H1P + col] = f2bs(v);
                }
        }
    }
    __syncthreads();

    // ---- Phase E: FC2 + resid (wave w covers 16 cols, M=32), K=512 from LDS ----
    {
        f32x4 acc[2] = {};
        #pragma unroll
        for (int kc = 0; kc < 512; kc += 128) {
            bf16x8 a2e[2][4], bfr[4];
            #pragma unroll
            for (int mt = 0; mt < 2; ++mt) {
                int rr = mt * 16 + rowf;
                #pragma unroll
                for (int t = 0; t < 4; ++t)
                    a2e[mt][t] = *(const bf16x8*)&h1s[rr * H1P + kc + t * 32 + kg * 8];
            }
            #pragma unroll
            for (int t = 0; t < 4; ++t)
                bfr[t] = (kc == 0) ? f2w0[t]
                       : *(const bf16x8*)(fc2_wt + (size_t)colB * HID + kc + t * 32 + kg * 8);
            #pragma unroll
            for (int t = 0; t < 4; ++t)
                #pragma unroll
                for (int mt = 0; mt < 2; ++mt)
                    acc[mt] = __builtin_amdgcn_mfma_f32_16x16x32_bf16(a2e[mt][t], bfr[t], acc[mt], 0, 0, 0);
        }
        float bv = fc2_b[colB];
        #pragma unroll
        for (int mt = 0; mt < 2; ++mt)
            #pragma unroll
            for (int r = 0; r < 4; ++r) {
                int row = mt * 16 + kg * 4 + r;
                out[(size_t)(R0 + row) * CC + colB] = acc[mt][r] + bv + x1s[row * X1P + colB];
            }
    }
}

extern "C" void kernel_launch(void* const* d_in, const int* in_sizes, int n_in,
                              void* d_out, int out_size, void* d_ws, size_t ws_size,
                              hipStream_t stream) {
    const float* x       = (const float*)d_in[0];
    const float* norm1_g = (const float*)d_in[1];
    const float* norm1_b = (const float*)d_in[2];
    const float* qkv_w   = (const float*)d_in[3];
    const float* qkv_b   = (const float*)d_in[4];
    const float* rpb     = (const float*)d_in[5];
    const float* proj_w  = (const float*)d_in[6];
    const float* proj_b  = (const float*)d_in[7];
    const float* norm2_g = (const float*)d_in[8];
    const float* norm2_b = (const float*)d_in[9];
    const float* fc1_w   = (const float*)d_in[10];
    const float* fc1_b   = (const float*)d_in[11];
    const float* fc2_w   = (const float*)d_in[12];
    const float* fc2_b   = (const float*)d_in[13];
    float* out = (float*)d_out;
    char* ws = (char*)d_ws;

    // workspace: qb [4][8192][32], kb, vbT [128][8192] (2MB each); wts single copy
    __hip_bfloat16* qb  = (__hip_bfloat16*)(ws);
    __hip_bfloat16* kb  = (__hip_bfloat16*)(ws + 2097152);
    __hip_bfloat16* vbT = (__hip_bfloat16*)(ws + 4194304);
    __hip_bfloat16* wts = (__hip_bfloat16*)(ws + 6291456);  // 196608 bf16 = 384 KB

    qkv_ln_kernel<<<NT / 32, 512, 0, stream>>>(x, norm1_g, norm1_b, qkv_w,
                                               proj_w, fc1_w, fc2_w, wts, qkv_b,
                                               qb, kb, vbT);
    mega_tail<<<NT / 32, 512, 0, stream>>>(qb, kb, vbT, rpb, x, wts, proj_b,
                                           norm2_g, norm2_b, fc1_b, fc2_b, out);
}